// Round 1
// baseline (547.293 us; speedup 1.0000x reference)
//
#include <hip/hip_runtime.h>
#include <cmath>

// Problem constants
#define SS   4096   // H*W
#define CCH  256    // C = N*d
#define NB   16     // batch
#define STILE 128   // s-tile
#define KCH  32     // K chunk

// ---------------------------------------------------------------------------
// Generic 256-row GEMM: Y[b,r,s] = sum_k W[r,k] * X[b,k,s]  (+ epilogue)
// grid (32, 2, 16), block 256. Tile 128r x 128s, micro 8x8.
// FFN=1: Y += bias[r] + res[b,r,s]
// ---------------------------------------------------------------------------
template<int FFN>
__global__ __launch_bounds__(256) void gemm256_kernel(
    const float* __restrict__ Xg,   // [16][256][4096]
    const float* __restrict__ Wg,   // [256][256]
    const float* __restrict__ bias, // [256] or nullptr
    const float* __restrict__ res,  // [16][256][4096] or nullptr
    float* __restrict__ Yg)         // [16][256][4096]
{
    const int t  = threadIdx.x;
    const int tx = t & 15;
    const int ty = t >> 4;
    const int s0 = blockIdx.x * STILE;
    const int r0 = blockIdx.y * 128;
    const int b  = blockIdx.z;

    __shared__ float Xs[KCH][STILE];
    __shared__ float Ws[KCH][132];   // transposed W tile, padded

    const float* Xb = Xg + (size_t)b * CCH * SS;

    float acc[8][8];
#pragma unroll
    for (int i = 0; i < 8; ++i)
#pragma unroll
        for (int j = 0; j < 8; ++j) acc[i][j] = 0.f;

    const int wr = t >> 1;          // 0..127  (W row within tile)
    const int wk = (t & 1) * 16;    // 0 / 16  (k offset)

    for (int k0 = 0; k0 < CCH; k0 += KCH) {
        // X tile: 32k x 128s, coalesced float4
#pragma unroll
        for (int p = 0; p < 4; ++p) {
            int f4  = p * 256 + t;
            int row = f4 >> 5, c4 = f4 & 31;
            float4 v = *(const float4*)(Xb + (size_t)(k0 + row) * SS + s0 + c4 * 4);
            *(float4*)&Xs[row][c4 * 4] = v;
        }
        // W tile transposed into Ws[k][r]
        {
            const float* Wrow = Wg + (size_t)(r0 + wr) * CCH + k0 + wk;
#pragma unroll
            for (int j4 = 0; j4 < 4; ++j4) {
                float4 wv = *(const float4*)(Wrow + j4 * 4);
                int kk = wk + j4 * 4;
                Ws[kk + 0][wr] = wv.x;
                Ws[kk + 1][wr] = wv.y;
                Ws[kk + 2][wr] = wv.z;
                Ws[kk + 3][wr] = wv.w;
            }
        }
        __syncthreads();
#pragma unroll
        for (int kk = 0; kk < KCH; ++kk) {
            float xv[8], wv[8];
            *(float4*)&xv[0] = *(const float4*)&Xs[kk][tx * 8];
            *(float4*)&xv[4] = *(const float4*)&Xs[kk][tx * 8 + 4];
            *(float4*)&wv[0] = *(const float4*)&Ws[kk][ty * 8];
            *(float4*)&wv[4] = *(const float4*)&Ws[kk][ty * 8 + 4];
#pragma unroll
            for (int i = 0; i < 8; ++i)
#pragma unroll
                for (int j = 0; j < 8; ++j)
                    acc[i][j] = fmaf(wv[i], xv[j], acc[i][j]);
        }
        __syncthreads();
    }

    float* Yb = Yg + (size_t)b * CCH * SS;
#pragma unroll
    for (int i = 0; i < 8; ++i) {
        int row   = r0 + ty * 8 + i;
        size_t off = (size_t)row * SS + s0 + tx * 8;
        float outv[8];
#pragma unroll
        for (int j = 0; j < 8; ++j) outv[j] = acc[i][j];
        if (FFN) {
            float bv = bias[row];
            const float* rp = res + (size_t)b * CCH * SS + off;
#pragma unroll
            for (int j = 0; j < 8; ++j) outv[j] += bv + rp[j];
        }
        *(float4*)(Yb + off)     = *(float4*)&outv[0];
        *(float4*)(Yb + off + 4) = *(float4*)&outv[4];
    }
}

// ---------------------------------------------------------------------------
// K+V projection (fused, reads fmaps once):
//   K[bn,r,s] = sum_c Wk[n,r,c]*F[bn,c,s];  V likewise. grid (32,1,64).
// Tile: 128 rows (64 K-rows stacked on 64 V-rows) x 128 s.
// ---------------------------------------------------------------------------
__global__ __launch_bounds__(256) void kv_kernel(
    const float* __restrict__ Fg,   // fmaps [64][256][4096]
    const float* __restrict__ Wk,   // [4][64][256]
    const float* __restrict__ Wv,   // [4][64][256]
    float* __restrict__ Kb,         // [64][64][4096]
    float* __restrict__ Vb)         // [64][64][4096]
{
    const int t  = threadIdx.x;
    const int tx = t & 15;
    const int ty = t >> 4;
    const int s0 = blockIdx.x * STILE;
    const int bn = blockIdx.z;
    const int n  = bn & 3;

    __shared__ float Xs[KCH][STILE];
    __shared__ float Ws[KCH][132];

    const float* Xb = Fg + (size_t)bn * CCH * SS;

    float acc[8][8];
#pragma unroll
    for (int i = 0; i < 8; ++i)
#pragma unroll
        for (int j = 0; j < 8; ++j) acc[i][j] = 0.f;

    const int wr = t >> 1;
    const int wk_ = (t & 1) * 16;
    const float* Wbase = (wr < 64)
        ? Wk + ((size_t)n * 64 + wr) * CCH
        : Wv + ((size_t)n * 64 + (wr - 64)) * CCH;

    for (int k0 = 0; k0 < CCH; k0 += KCH) {
#pragma unroll
        for (int p = 0; p < 4; ++p) {
            int f4  = p * 256 + t;
            int row = f4 >> 5, c4 = f4 & 31;
            float4 v = *(const float4*)(Xb + (size_t)(k0 + row) * SS + s0 + c4 * 4);
            *(float4*)&Xs[row][c4 * 4] = v;
        }
        {
            const float* Wrow = Wbase + k0 + wk_;
#pragma unroll
            for (int j4 = 0; j4 < 4; ++j4) {
                float4 wv = *(const float4*)(Wrow + j4 * 4);
                int kk = wk_ + j4 * 4;
                Ws[kk + 0][wr] = wv.x;
                Ws[kk + 1][wr] = wv.y;
                Ws[kk + 2][wr] = wv.z;
                Ws[kk + 3][wr] = wv.w;
            }
        }
        __syncthreads();
#pragma unroll
        for (int kk = 0; kk < KCH; ++kk) {
            float xv[8], wv[8];
            *(float4*)&xv[0] = *(const float4*)&Xs[kk][tx * 8];
            *(float4*)&xv[4] = *(const float4*)&Xs[kk][tx * 8 + 4];
            *(float4*)&wv[0] = *(const float4*)&Ws[kk][ty * 8];
            *(float4*)&wv[4] = *(const float4*)&Ws[kk][ty * 8 + 4];
#pragma unroll
            for (int i = 0; i < 8; ++i)
#pragma unroll
                for (int j = 0; j < 8; ++j)
                    acc[i][j] = fmaf(wv[i], xv[j], acc[i][j]);
        }
        __syncthreads();
    }

#pragma unroll
    for (int i = 0; i < 8; ++i) {
        int row = ty * 8 + i;   // 0..127
        float* Yb = (row < 64) ? Kb + ((size_t)bn * 64 + row) * SS
                               : Vb + ((size_t)bn * 64 + (row - 64)) * SS;
        *(float4*)(Yb + s0 + tx * 8)     = *(float4*)&acc[i][0];
        *(float4*)(Yb + s0 + tx * 8 + 4) = *(float4*)&acc[i][4];
    }
}

// ---------------------------------------------------------------------------
// Row L2 inverse norms over s (4096). grid 8192 (4096 q rows + 4096 k rows).
// ---------------------------------------------------------------------------
__global__ __launch_bounds__(256) void norm_kernel(
    const float* __restrict__ q, const float* __restrict__ k,
    float* __restrict__ invq, float* __restrict__ invk)
{
    int row = blockIdx.x;
    const float* p = (row < 4096) ? q + (size_t)row * SS
                                  : k + (size_t)(row - 4096) * SS;
    int t = threadIdx.x;
    float s = 0.f;
#pragma unroll
    for (int p4 = 0; p4 < 4; ++p4) {
        float4 v = *(const float4*)(p + (size_t)(p4 * 256 + t) * 4);
        s += v.x * v.x + v.y * v.y + v.z * v.z + v.w * v.w;
    }
    __shared__ float red[256];
    red[t] = s;
    __syncthreads();
    for (int off = 128; off > 0; off >>= 1) {
        if (t < off) red[t] += red[t + off];
        __syncthreads();
    }
    if (t == 0) {
        float inv = 1.0f / fmaxf(sqrtf(red[0]), 1e-12f);
        if (row < 4096) invq[row] = inv;
        else            invk[row - 4096] = inv;
    }
}

// ---------------------------------------------------------------------------
// attn partial: part[bn,chunk,dd,e] = sum_{s in chunk} k[dd,s]*q[e,s]
// grid (4, 64), block 256; each thread 4dd x 4e.
// ---------------------------------------------------------------------------
__global__ __launch_bounds__(256) void attn_partial_kernel(
    const float* __restrict__ q, const float* __restrict__ k,
    float* __restrict__ part)
{
    const int chunk = blockIdx.x;   // 0..3
    const int bn    = blockIdx.y;   // 0..63
    const int t = threadIdx.x;
    const int dd4 = (t >> 4) * 4;
    const int e4  = (t & 15) * 4;

    const float* krows = k + (size_t)bn * 64 * SS;
    const float* qrows = q + (size_t)bn * 64 * SS;

    __shared__ float kt[64][65];
    __shared__ float qt[64][65];

    float acc[4][4];
#pragma unroll
    for (int i = 0; i < 4; ++i)
#pragma unroll
        for (int j = 0; j < 4; ++j) acc[i][j] = 0.f;

    const int send = chunk * 1024 + 1024;
    for (int s0 = chunk * 1024; s0 < send; s0 += 64) {
        __syncthreads();
#pragma unroll
        for (int p = 0; p < 4; ++p) {
            int f4 = p * 256 + t;
            int row = f4 >> 4, c4 = (f4 & 15) * 4;
            float4 kv = *(const float4*)(krows + (size_t)row * SS + s0 + c4);
            float4 qv = *(const float4*)(qrows + (size_t)row * SS + s0 + c4);
            kt[row][c4 + 0] = kv.x; kt[row][c4 + 1] = kv.y;
            kt[row][c4 + 2] = kv.z; kt[row][c4 + 3] = kv.w;
            qt[row][c4 + 0] = qv.x; qt[row][c4 + 1] = qv.y;
            qt[row][c4 + 2] = qv.z; qt[row][c4 + 3] = qv.w;
        }
        __syncthreads();
#pragma unroll 8
        for (int ss = 0; ss < 64; ++ss) {
            float kvv[4], qvv[4];
#pragma unroll
            for (int i = 0; i < 4; ++i) kvv[i] = kt[dd4 + i][ss];
#pragma unroll
            for (int j = 0; j < 4; ++j) qvv[j] = qt[e4 + j][ss];
#pragma unroll
            for (int i = 0; i < 4; ++i)
#pragma unroll
                for (int j = 0; j < 4; ++j)
                    acc[i][j] = fmaf(kvv[i], qvv[j], acc[i][j]);
        }
    }

    float* pp = part + ((size_t)bn * 4 + chunk) * 4096;
#pragma unroll
    for (int i = 0; i < 4; ++i)
#pragma unroll
        for (int j = 0; j < 4; ++j)
            pp[(dd4 + i) * 64 + (e4 + j)] = acc[i][j];
}

// ---------------------------------------------------------------------------
// attn finalize: sum partials, scale by invk*invq*rescale, row softmax.
// grid 64 (bn), block 256.
// ---------------------------------------------------------------------------
__global__ __launch_bounds__(256) void attn_finalize_kernel(
    const float* __restrict__ part,
    const float* __restrict__ invq, const float* __restrict__ invk,
    const float* __restrict__ rescale,
    float* __restrict__ attn_out)   // [64][64][64]
{
    const int bn = blockIdx.x;
    const int n  = bn & 3;
    const int t  = threadIdx.x;
    const float rs = rescale[n];

    __shared__ float att[64][65];
    __shared__ float rmax[64], rsum[64];

    const float* pb = part + (size_t)bn * 4 * 4096;
#pragma unroll
    for (int p = 0; p < 16; ++p) {
        int lin = p * 256 + t;
        int dd = lin >> 6, e = lin & 63;
        float v = pb[lin] + pb[4096 + lin] + pb[8192 + lin] + pb[12288 + lin];
        v *= invk[bn * 64 + dd] * invq[bn * 64 + e] * rs;
        att[dd][e] = v;
    }
    __syncthreads();
    if (t < 64) {
        float m = -1e30f;
        for (int e = 0; e < 64; ++e) m = fmaxf(m, att[t][e]);
        float s = 0.f;
        for (int e = 0; e < 64; ++e) s += expf(att[t][e] - m);
        rmax[t] = m;
        rsum[t] = 1.0f / s;
    }
    __syncthreads();
    float* ob = attn_out + (size_t)bn * 4096;
#pragma unroll
    for (int p = 0; p < 16; ++p) {
        int lin = p * 256 + t;
        int dd = lin >> 6, e = lin & 63;
        ob[lin] = expf(att[dd][e] - rmax[dd]) * rsum[dd];
    }
}

// ---------------------------------------------------------------------------
// PV: O[bn,dd,s] = sum_e attn[bn,dd,e]*V[bn,e,s] + q[bn*64+dd, s]
// grid (32,1,64). Tile 64dd x 128s, micro 4x8. Writes into k-buffer (reuse).
// ---------------------------------------------------------------------------
__global__ __launch_bounds__(256) void pv_kernel(
    const float* __restrict__ Attn, // [64][64][64]
    const float* __restrict__ Vb,   // [64][64][4096]
    const float* __restrict__ Qb,   // [16][256][4096]
    float* __restrict__ Ob)         // [16][256][4096]
{
    const int t  = threadIdx.x;
    const int tx = t & 15;
    const int ty = t >> 4;
    const int s0 = blockIdx.x * STILE;
    const int bn = blockIdx.z;

    __shared__ float Wst[64][68];    // transposed attn: Wst[e][dd]
    __shared__ float Xs[64][STILE];  // V tile

    const float* Ab = Attn + (size_t)bn * 4096;
#pragma unroll
    for (int p = 0; p < 4; ++p) {
        int f4 = p * 256 + t;
        int dd = f4 >> 4, e4 = (f4 & 15) * 4;
        float4 av = *(const float4*)(Ab + dd * 64 + e4);
        Wst[e4 + 0][dd] = av.x; Wst[e4 + 1][dd] = av.y;
        Wst[e4 + 2][dd] = av.z; Wst[e4 + 3][dd] = av.w;
    }
    const float* Vbb = Vb + (size_t)bn * 64 * SS;
#pragma unroll
    for (int p = 0; p < 8; ++p) {
        int f4 = p * 256 + t;
        int row = f4 >> 5, c4 = f4 & 31;
        *(float4*)&Xs[row][c4 * 4] = *(const float4*)(Vbb + (size_t)row * SS + s0 + c4 * 4);
    }
    __syncthreads();

    float acc[4][8];
#pragma unroll
    for (int i = 0; i < 4; ++i)
#pragma unroll
        for (int j = 0; j < 8; ++j) acc[i][j] = 0.f;

#pragma unroll 8
    for (int kk = 0; kk < 64; ++kk) {
        float wv[4], xv[8];
        *(float4*)&wv[0] = *(const float4*)&Wst[kk][ty * 4];
        *(float4*)&xv[0] = *(const float4*)&Xs[kk][tx * 8];
        *(float4*)&xv[4] = *(const float4*)&Xs[kk][tx * 8 + 4];
#pragma unroll
        for (int i = 0; i < 4; ++i)
#pragma unroll
            for (int j = 0; j < 8; ++j)
                acc[i][j] = fmaf(wv[i], xv[j], acc[i][j]);
    }

#pragma unroll
    for (int i = 0; i < 4; ++i) {
        int row = ty * 4 + i;
        size_t off = ((size_t)bn * 64 + row) * SS + s0 + tx * 8;
        float outv[8];
#pragma unroll
        for (int j = 0; j < 8; ++j) outv[j] = acc[i][j] + Qb[off + j];
        *(float4*)(Ob + off)     = *(float4*)&outv[0];
        *(float4*)(Ob + off + 4) = *(float4*)&outv[4];
    }
}

// ---------------------------------------------------------------------------
extern "C" void kernel_launch(void* const* d_in, const int* in_sizes, int n_in,
                              void* d_out, int out_size, void* d_ws, size_t ws_size,
                              hipStream_t stream) {
    const float* x       = (const float*)d_in[0];
    const float* fmaps   = (const float*)d_in[1];
    const float* Wq      = (const float*)d_in[2];
    const float* Wk      = (const float*)d_in[3];
    const float* Wv      = (const float*)d_in[4];
    const float* rescale = (const float*)d_in[5];
    const float* Wffn    = (const float*)d_in[6];
    const float* bffn    = (const float*)d_in[7];
    float* out = (float*)d_out;

    const size_t BIG = (size_t)NB * CCH * SS;   // 16,777,216 floats
    float* q     = (float*)d_ws;
    float* kbuf  = q + BIG;
    float* vbuf  = kbuf + BIG;
    float* part  = vbuf + BIG;                  // 64*4*4096
    float* attnb = part + (size_t)64 * 4 * 4096;
    float* invq  = attnb + (size_t)64 * 4096;
    float* invk  = invq + 4096;

    dim3 blk(256);
    // 1. Q projection: q[b,o,s] = sum_c Wq[o,c] x[b,c,s]
    gemm256_kernel<0><<<dim3(32, 2, 16), blk, 0, stream>>>(x, Wq, nullptr, nullptr, q);
    // 2. K/V projections (fused fmaps read)
    kv_kernel<<<dim3(32, 1, 64), blk, 0, stream>>>(fmaps, Wk, Wv, kbuf, vbuf);
    // 3. inverse L2 norms of q and k rows
    norm_kernel<<<dim3(8192), blk, 0, stream>>>(q, kbuf, invq, invk);
    // 4. attn partial dot products over s-chunks
    attn_partial_kernel<<<dim3(4, 64), blk, 0, stream>>>(q, kbuf, part);
    // 5. combine partials, scale, softmax
    attn_finalize_kernel<<<dim3(64), blk, 0, stream>>>(part, invq, invk, rescale, attnb);
    // 6. PV + q residual -> outp (reuse kbuf)
    pv_kernel<<<dim3(32, 1, 64), blk, 0, stream>>>(attnb, vbuf, q, kbuf);
    // 7. FFN + bffn + q residual -> final output
    gemm256_kernel<1><<<dim3(32, 2, 16), blk, 0, stream>>>(kbuf, Wffn, bffn, q, out);
}

// Round 2
// 289.631 us; speedup vs baseline: 1.8896x; 1.8896x over previous
//
#include <hip/hip_runtime.h>
#include <hip/hip_bf16.h>
#include <cmath>

using bf16 = __hip_bfloat16;
typedef __attribute__((ext_vector_type(4))) float  f32x4;
typedef __attribute__((ext_vector_type(8))) short  bf16x8;
typedef unsigned int u32;
typedef unsigned short u16;

// ---------------------------------------------------------------------------
// async global->LDS, 16B per lane (guide §5; m97 pattern)
// ---------------------------------------------------------------------------
__device__ __forceinline__ void gl_lds16(const bf16* g, bf16* l) {
    __builtin_amdgcn_global_load_lds(
        (const __attribute__((address_space(1))) u32*)g,
        (__attribute__((address_space(3))) u32*)l, 16, 0, 0);
}

// ---------------------------------------------------------------------------
// Unified bf16 MFMA GEMM:  Y[m][n] = sum_k A[m][k] * B[n][k]   (C = A·B^T)
// A: [M][K] row-major k-contig (ldA), B: [N][K] row-major k-contig (ldB).
// Tiles: BM x BN, BK=64, 4 waves (2x2), wave tile BM/2 x BN/2.
// LDS staged via global_load_lds with (row&7) XOR chunk swizzle (16B chunks).
// EPI: 0 = bf16 out; 1 = bf16 out + bf16 res; 2 = f32 out + bias + bf16 res;
//      3 = f32 out plain.
// batch: bz=blockIdx.z, hi=bz>>bshift, lo=bz&mask; ptr += hi*sXhi + lo*sXlo.
// ---------------------------------------------------------------------------
template<int BM, int BN, int EPI>
__global__ __launch_bounds__(256) void gemm_bt(
    const bf16* __restrict__ Ab, const bf16* __restrict__ Bb,
    void* __restrict__ Yb, const bf16* __restrict__ Rb,
    const float* __restrict__ bias,
    int K, int ldA, int ldB, int ldY, int bshift,
    long sAhi, long sAlo, long sBhi, long sBlo, long sYhi, long sYlo)
{
    constexpr int WM = BM / 2, WN = BN / 2;
    constexpr int MF = WM / 16, NF = WN / 16;
    __shared__ bf16 sA[BM * 64];
    __shared__ bf16 sB[BN * 64];

    const int t = threadIdx.x;
    const int lane = t & 63;
    const int wid = t >> 6;
    const int wm = wid >> 1, wn = wid & 1;
    const int g = lane >> 4, lr = lane & 15;

    const int bz = blockIdx.z;
    const long hi = bz >> bshift;
    const long lo = bz & ((1 << bshift) - 1);
    const bf16* A = Ab + hi * sAhi + lo * sAlo + (long)blockIdx.y * BM * ldA;
    const bf16* B = Bb + hi * sBhi + lo * sBlo + (long)blockIdx.x * BN * ldB;

    f32x4 acc[MF][NF];
#pragma unroll
    for (int mf = 0; mf < MF; ++mf)
#pragma unroll
        for (int nf = 0; nf < NF; ++nf) acc[mf][nf] = (f32x4){0.f, 0.f, 0.f, 0.f};

    for (int k0 = 0; k0 < K; k0 += 64) {
        __syncthreads();   // prior compute done with LDS
        // stage A tile [BM][64] (8 chunks/row, pre-swizzled source)
#pragma unroll
        for (int i = 0; i < BM / 32; ++i) {
            int lin = i * 256 + t;
            int r = lin >> 3, ch = lin & 7;
            gl_lds16(A + (long)r * ldA + k0 + ((ch ^ (r & 7)) << 3), &sA[lin * 8]);
        }
#pragma unroll
        for (int i = 0; i < BN / 32; ++i) {
            int lin = i * 256 + t;
            int r = lin >> 3, ch = lin & 7;
            gl_lds16(B + (long)r * ldB + k0 + ((ch ^ (r & 7)) << 3), &sB[lin * 8]);
        }
        __syncthreads();   // compiler drains vmcnt before barrier

#pragma unroll
        for (int kk = 0; kk < 2; ++kk) {
            bf16x8 af[MF], bfr[NF];
#pragma unroll
            for (int mf = 0; mf < MF; ++mf) {
                int r = wm * WM + mf * 16 + lr;
                int ch = (kk * 4 + g) ^ (r & 7);
                af[mf] = *(const bf16x8*)((const char*)sA + r * 128 + ch * 16);
            }
#pragma unroll
            for (int nf = 0; nf < NF; ++nf) {
                int r = wn * WN + nf * 16 + lr;
                int ch = (kk * 4 + g) ^ (r & 7);
                bfr[nf] = *(const bf16x8*)((const char*)sB + r * 128 + ch * 16);
            }
#pragma unroll
            for (int mf = 0; mf < MF; ++mf)
#pragma unroll
                for (int nf = 0; nf < NF; ++nf)
                    acc[mf][nf] = __builtin_amdgcn_mfma_f32_16x16x32_bf16(
                        af[mf], bfr[nf], acc[mf][nf], 0, 0, 0);
        }
    }

    // epilogue: D[(l>>4)*4+e][l&15] per 16x16 frag
    const long ybase = hi * sYhi + lo * sYlo;
    const int m0 = blockIdx.y * BM + wm * WM;
    const int n0 = blockIdx.x * BN + wn * WN;
#pragma unroll
    for (int mf = 0; mf < MF; ++mf)
#pragma unroll
        for (int nf = 0; nf < NF; ++nf)
#pragma unroll
            for (int e = 0; e < 4; ++e) {
                int m = m0 + mf * 16 + g * 4 + e;
                int n = n0 + nf * 16 + lr;
                long idx = ybase + (long)m * ldY + n;
                float v = acc[mf][nf][e];
                if (EPI == 1 || EPI == 2) v += __bfloat162float(Rb[idx]);
                if (EPI == 2) v += bias[m];
                if (EPI == 0 || EPI == 1)
                    ((bf16*)Yb)[idx] = __float2bfloat16(v);
                else
                    ((float*)Yb)[idx] = v;
            }
}

// ---------------------------------------------------------------------------
// Transpose-convert: src f32 [Bt][256][4096] -> dst bf16 [Bt][4096][256]
// block: 64c x 128s tile; LDS row stride 130 bf16 (bank-spread)
// ---------------------------------------------------------------------------
__global__ __launch_bounds__(256) void tconv(
    const float* __restrict__ src, bf16* __restrict__ dst)
{
    __shared__ bf16 tile[64 * 130];
    const int t = threadIdx.x;
    const int s0 = blockIdx.x * 128, c0 = blockIdx.y * 64;
    const long bo = (long)blockIdx.z * (256L * 4096);
    const int cl = t >> 5, s4 = (t & 31) * 4;
#pragma unroll
    for (int p = 0; p < 8; ++p) {
        int c = p * 8 + cl;
        float4 v = *(const float4*)(src + bo + (long)(c0 + c) * 4096 + s0 + s4);
        bf16* d = &tile[c * 130 + s4];
        d[0] = __float2bfloat16(v.x); d[1] = __float2bfloat16(v.y);
        d[2] = __float2bfloat16(v.z); d[3] = __float2bfloat16(v.w);
    }
    __syncthreads();
    const long bo2 = (long)blockIdx.z * (4096L * 256);
#pragma unroll
    for (int w = 0; w < 4; ++w) {
        int idx = w * 256 + t;
        int s = idx >> 3, cc = (idx & 7) * 8;
        u16 o[8];
#pragma unroll
        for (int j = 0; j < 8; ++j)
            o[j] = ((const u16*)tile)[(cc + j) * 130 + s];
        uint4 pk;
        pk.x = (u32)o[0] | ((u32)o[1] << 16);
        pk.y = (u32)o[2] | ((u32)o[3] << 16);
        pk.z = (u32)o[4] | ((u32)o[5] << 16);
        pk.w = (u32)o[6] | ((u32)o[7] << 16);
        *(uint4*)(dst + bo2 + (long)(s0 + s) * 256 + c0 + cc) = pk;
    }
}

// ---------------------------------------------------------------------------
// Weight convert f32 -> bf16: [Wq | Wk | Wv | Wffn], 65536 each
// ---------------------------------------------------------------------------
__global__ __launch_bounds__(256) void wconv(
    const float* __restrict__ a, const float* __restrict__ b,
    const float* __restrict__ c, const float* __restrict__ d,
    bf16* __restrict__ o)
{
    int i = blockIdx.x * 256 + threadIdx.x;   // 0..262143
    int which = i >> 16, off = i & 65535;
    const float* s = (which == 0) ? a : (which == 1) ? b : (which == 2) ? c : d;
    o[i] = __float2bfloat16(s[off]);
}

// ---------------------------------------------------------------------------
// Row inverse L2 norms over s=4096 (bf16 input). grid 8192.
// ---------------------------------------------------------------------------
__global__ __launch_bounds__(256) void normk(
    const bf16* __restrict__ qch, const bf16* __restrict__ kb,
    float* __restrict__ invq, float* __restrict__ invk)
{
    int row = blockIdx.x;
    const bf16* base = (row < 4096) ? qch + (long)row * 4096
                                    : kb + (long)(row - 4096) * 4096;
    int t = threadIdx.x;
    float s = 0.f;
#pragma unroll
    for (int h = 0; h < 2; ++h) {
        uint4 v = *(const uint4*)(base + h * 2048 + t * 8);
        u32 ws[4] = {v.x, v.y, v.z, v.w};
#pragma unroll
        for (int j = 0; j < 4; ++j) {
            float lo = __uint_as_float(ws[j] << 16);
            float hi2 = __uint_as_float(ws[j] & 0xffff0000u);
            s += lo * lo + hi2 * hi2;
        }
    }
    __shared__ float red[256];
    red[t] = s;
    __syncthreads();
    for (int off = 128; off > 0; off >>= 1) {
        if (t < off) red[t] += red[t + off];
        __syncthreads();
    }
    if (t == 0) {
        float inv = 1.0f / fmaxf(sqrtf(red[0]), 1e-12f);
        if (row < 4096) invq[row] = inv;
        else            invk[row - 4096] = inv;
    }
}

// ---------------------------------------------------------------------------
// finalize: sum K-split partials, scale by invk*invq*rescale, softmax -> bf16
// ---------------------------------------------------------------------------
__global__ __launch_bounds__(256) void attn_finalize_kernel(
    const float* __restrict__ part,
    const float* __restrict__ invq, const float* __restrict__ invk,
    const float* __restrict__ rescale,
    bf16* __restrict__ attn_out)
{
    const int bn = blockIdx.x;
    const int n = bn & 3;
    const int t = threadIdx.x;
    const float rs = rescale[n];

    __shared__ float att[64][65];
    __shared__ float rmax[64], rsum[64];

    const float* pb = part + (size_t)bn * 4 * 4096;
#pragma unroll
    for (int p = 0; p < 16; ++p) {
        int lin = p * 256 + t;
        int dd = lin >> 6, e = lin & 63;
        float v = pb[lin] + pb[4096 + lin] + pb[8192 + lin] + pb[12288 + lin];
        v *= invk[bn * 64 + dd] * invq[bn * 64 + e] * rs;
        att[dd][e] = v;
    }
    __syncthreads();
    if (t < 64) {
        float m = -1e30f;
        for (int e = 0; e < 64; ++e) m = fmaxf(m, att[t][e]);
        float sm = 0.f;
        for (int e = 0; e < 64; ++e) sm += expf(att[t][e] - m);
        rmax[t] = m;
        rsum[t] = 1.0f / sm;
    }
    __syncthreads();
    bf16* ob = attn_out + (size_t)bn * 4096;
#pragma unroll
    for (int p = 0; p < 16; ++p) {
        int lin = p * 256 + t;
        int dd = lin >> 6, e = lin & 63;
        ob[lin] = __float2bfloat16(expf(att[dd][e] - rmax[dd]) * rsum[dd]);
    }
}

// ---------------------------------------------------------------------------
extern "C" void kernel_launch(void* const* d_in, const int* in_sizes, int n_in,
                              void* d_out, int out_size, void* d_ws, size_t ws_size,
                              hipStream_t stream) {
    const float* x       = (const float*)d_in[0];
    const float* fmaps   = (const float*)d_in[1];
    const float* Wq      = (const float*)d_in[2];
    const float* Wk      = (const float*)d_in[3];
    const float* Wv      = (const float*)d_in[4];
    const float* rescale = (const float*)d_in[5];
    const float* Wffn    = (const float*)d_in[6];
    const float* bffn    = (const float*)d_in[7];
    float* out = (float*)d_out;

    char* w = (char*)d_ws;
    // byte layout (total ~133 MB)
    bf16* xT   = (bf16*)(w + 0);              // 33.55 MB; reused as k, then Z
    bf16* kbuf = xT;
    bf16* Z    = xT;
    bf16* qT   = (bf16*)(w + 33554432L);
    bf16* vT   = (bf16*)(w + 67108864L);
    bf16* qch  = (bf16*)(w + 100663296L);
    float* part = (float*)(w + 134217728L);   // 64*4*4096 f32 = 4.19 MB
    bf16* attnb = (bf16*)(w + 138412032L);    // 64*4096 bf16
    float* invq = (float*)(w + 138936320L);
    float* invk = (float*)(w + 138952704L);
    bf16* Wq_b  = (bf16*)(w + 138969088L);
    bf16* Wk_b  = Wq_b + 65536;
    bf16* Wv_b  = Wq_b + 131072;
    bf16* Wf_b  = Wq_b + 196608;
    bf16* fTq   = (bf16*)d_out;               // 33.55 MB scratch (overwritten by FFN)

    dim3 blk(256);
    const long BS = 1048576;   // 4096*256 (elements per batch, s-major)

    // 1. weights -> bf16
    wconv<<<dim3(1024), blk, 0, stream>>>(Wq, Wk, Wv, Wffn, Wq_b);
    // 2. x -> xT (s-major bf16)
    tconv<<<dim3(32, 4, 16), blk, 0, stream>>>(x, xT);
    // 3. Q ch-major: qch[b][o][s] = sum_c Wq[o][c]*xT[b][s][c]
    gemm_bt<128, 128, 0><<<dim3(32, 2, 16), blk, 0, stream>>>(
        Wq_b, xT, qch, nullptr, nullptr,
        256, 256, 256, 4096, 0, 0, 0, BS, 0, BS, 0);
    // 4. Q s-major: qT[b][s][o]
    gemm_bt<128, 128, 0><<<dim3(2, 32, 16), blk, 0, stream>>>(
        xT, Wq_b, qT, nullptr, nullptr,
        256, 256, 256, 256, 0, BS, 0, 0, 0, BS, 0);
    // 5. per-quarter: fmaps -> fTq; K and V projections   (xT dead: k overlays)
    for (int qi = 0; qi < 4; ++qi) {
        tconv<<<dim3(32, 4, 16), blk, 0, stream>>>(fmaps + (long)qi * 16 * BS, fTq);
        // k[bn][dd][s] = sum_c Wk[n][dd][c] * fTq[bz][s][c]
        gemm_bt<64, 128, 0><<<dim3(32, 1, 16), blk, 0, stream>>>(
            Wk_b, fTq, kbuf + (long)qi * 16 * 262144, nullptr, nullptr,
            256, 256, 256, 4096, 2,
            0, 16384, 4 * BS, BS, 1048576, 262144);
        // vT[bn][s][e] = sum_c fTq[bz][s][c] * Wv[n][e][c]
        gemm_bt<128, 64, 0><<<dim3(1, 32, 16), blk, 0, stream>>>(
            fTq, Wv_b, vT + (long)qi * 16 * 262144, nullptr, nullptr,
            256, 256, 256, 64, 2,
            4 * BS, BS, 0, 16384, 1048576, 262144);
    }
    // 6. inverse L2 norms of q (rows 0..4095) and k (rows 4096..8191)
    normk<<<dim3(8192), blk, 0, stream>>>(qch, kbuf, invq, invk);
    // 7. QK^T partials over 4 s-chunks: part[bn*4+ch][dd][e]
    gemm_bt<64, 64, 3><<<dim3(1, 1, 256), blk, 0, stream>>>(
        kbuf, qch, part, nullptr, nullptr,
        1024, 4096, 4096, 64, 2,
        262144, 1024, 262144, 1024, 16384, 4096);
    // 8. finalize: scale + softmax -> attn bf16
    attn_finalize_kernel<<<dim3(64), blk, 0, stream>>>(part, invq, invk, rescale, attnb);
    // 9. PV + qT residual -> Z[b][s][n*64+dd]   (k dead: Z overlays)
    gemm_bt<128, 64, 1><<<dim3(1, 32, 64), blk, 0, stream>>>(
        vT, attnb, Z, qT, nullptr,
        64, 64, 64, 256, 2,
        BS, 262144, 16384, 4096, BS, 64);
    // 10. FFN + bffn + qch residual -> out f32 [b][c][s]
    gemm_bt<128, 128, 2><<<dim3(32, 2, 16), blk, 0, stream>>>(
        Wf_b, Z, out, qch, bffn,
        256, 256, 256, 4096, 0,
        0, 0, BS, 0, BS, 0);
}

// Round 3
// 201.251 us; speedup vs baseline: 2.7194x; 1.4392x over previous
//
#include <hip/hip_runtime.h>
#include <hip/hip_bf16.h>
#include <cmath>

using bf16 = __hip_bfloat16;
typedef __attribute__((ext_vector_type(4))) float  f32x4;
typedef __attribute__((ext_vector_type(8))) short  bf16x8;
typedef unsigned int u32;
typedef unsigned short u16;

// async global->LDS, 16B per lane
__device__ __forceinline__ void gl_lds16(const bf16* g, bf16* l) {
    __builtin_amdgcn_global_load_lds(
        (const __attribute__((address_space(1))) u32*)g,
        (__attribute__((address_space(3))) u32*)l, 16, 0, 0);
}

__device__ __forceinline__ u32 pk2(float a, float b) {
    bf16 ha = __float2bfloat16(a), hb = __float2bfloat16(b);
    return (u32)*(u16*)&ha | ((u32)*(u16*)&hb << 16);
}

// ---------------------------------------------------------------------------
// Q projection, fused transpose-convert of x.
// qch[b][o][s] = sum_c Wq[o][c] * x[b][c][s]
// grid (32 s-tiles, 2 o-tiles, 16 b), block 256 (4 waves 2x2).
// ---------------------------------------------------------------------------
__global__ __launch_bounds__(256) void qproj(
    const float* __restrict__ x,   // [16][256][4096]
    const bf16* __restrict__ Wq,   // [256][256]
    bf16* __restrict__ qch)        // [16][256][4096]
{
    __shared__ bf16 sW[128 * 64];  // [o][64c], chunk-XOR swizzled
    __shared__ bf16 sX[128 * 72];  // [s][c], 144B padded rows
    const int t = threadIdx.x;
    const int lane = t & 63, wid = t >> 6;
    const int wm = wid >> 1, wn = wid & 1;
    const int g = lane >> 4, lr = lane & 15;
    const int s0 = blockIdx.x * 128;
    const int o0 = blockIdx.y * 128;
    const float* xb = x + (long)blockIdx.z * 1048576;

    f32x4 acc[4][4];
#pragma unroll
    for (int i = 0; i < 4; ++i)
#pragma unroll
        for (int j = 0; j < 4; ++j) acc[i][j] = (f32x4){0.f, 0.f, 0.f, 0.f};

    const int p  = t & 31;   // c-pair
    const int sl = t >> 5;   // 0..7

    for (int c0 = 0; c0 < 256; c0 += 64) {
        __syncthreads();
#pragma unroll
        for (int i = 0; i < 4; ++i) {
            int lin = i * 256 + t, r = lin >> 3, ch = lin & 7;
            gl_lds16(Wq + (long)(o0 + r) * 256 + c0 + ((ch ^ (r & 7)) << 3), &sW[lin * 8]);
        }
#pragma unroll
        for (int j = 0; j < 4; ++j) {
            int s4 = j * 8 + sl;
            const float* src = xb + (long)(c0 + 2 * p) * 4096 + s0 + s4 * 4;
            float4 a = *(const float4*)src;
            float4 bq = *(const float4*)(src + 4096);
            char* base = (char*)sX + p * 4 + (s4 * 4) * 144;
            *(u32*)(base +   0) = pk2(a.x, bq.x);
            *(u32*)(base + 144) = pk2(a.y, bq.y);
            *(u32*)(base + 288) = pk2(a.z, bq.z);
            *(u32*)(base + 432) = pk2(a.w, bq.w);
        }
        __syncthreads();
#pragma unroll
        for (int kk = 0; kk < 2; ++kk) {
            bf16x8 aw[4], fx[4];
#pragma unroll
            for (int mf = 0; mf < 4; ++mf) {
                int r = wm * 64 + mf * 16 + lr;
                int ch = (kk * 4 + g) ^ (r & 7);
                aw[mf] = *(const bf16x8*)((const char*)sW + r * 128 + ch * 16);
            }
#pragma unroll
            for (int nf = 0; nf < 4; ++nf) {
                int s = wn * 64 + nf * 16 + lr;
                fx[nf] = *(const bf16x8*)((const char*)sX + s * 144 + (kk * 4 + g) * 16);
            }
#pragma unroll
            for (int mf = 0; mf < 4; ++mf)
#pragma unroll
                for (int nf = 0; nf < 4; ++nf)
                    acc[mf][nf] = __builtin_amdgcn_mfma_f32_16x16x32_bf16(
                        aw[mf], fx[nf], acc[mf][nf], 0, 0, 0);
        }
    }
    bf16* qb = qch + (long)blockIdx.z * 1048576;
#pragma unroll
    for (int mf = 0; mf < 4; ++mf)
#pragma unroll
        for (int nf = 0; nf < 4; ++nf)
#pragma unroll
            for (int e = 0; e < 4; ++e) {
                int o = o0 + wm * 64 + mf * 16 + g * 4 + e;
                int s = s0 + wn * 64 + nf * 16 + lr;
                qb[(long)o * 4096 + s] = __float2bfloat16(acc[mf][nf][e]);
            }
}

// ---------------------------------------------------------------------------
// K+V projection, fused transpose-convert of fmaps (read once).
// kb[bn][dd][s] = sum_c Wk[n][dd][c]*fm[bn][c][s]
// vT[bn][s][e]  = sum_c fm[bn][c][s]*Wv[n][e][c]
// grid (32 s-tiles, 64 bn), block 256; wave w owns s-quarter w*32.
// ---------------------------------------------------------------------------
__global__ __launch_bounds__(256) void kvproj(
    const float* __restrict__ fm,  // [64][256][4096]
    const bf16* __restrict__ Wk,   // [4][64][256]
    const bf16* __restrict__ Wv,   // [4][64][256]
    bf16* __restrict__ kb,         // [64][64][4096]
    bf16* __restrict__ vT)         // [64][4096][64]
{
    __shared__ bf16 sF[128 * 72];  // [s][c] padded
    __shared__ bf16 sK[64 * 64];
    __shared__ bf16 sV[64 * 64];
    const int t = threadIdx.x;
    const int lane = t & 63, wid = t >> 6;
    const int g = lane >> 4, lr = lane & 15;
    const int s0 = blockIdx.x * 128;
    const int bn = blockIdx.y, n = bn & 3;
    const float* fb = fm + (long)bn * 1048576;
    const bf16* WkN = Wk + (long)n * 16384;
    const bf16* WvN = Wv + (long)n * 16384;

    f32x4 acc1[4][2];   // K: [dd-frag][s-frag]
    f32x4 acc2[2][4];   // V: [s-frag][e-frag]
#pragma unroll
    for (int i = 0; i < 4; ++i)
#pragma unroll
        for (int j = 0; j < 2; ++j) {
            acc1[i][j] = (f32x4){0.f, 0.f, 0.f, 0.f};
            acc2[j][i] = (f32x4){0.f, 0.f, 0.f, 0.f};
        }

    const int p  = t & 31;
    const int sl = t >> 5;

    for (int c0 = 0; c0 < 256; c0 += 64) {
        __syncthreads();
#pragma unroll
        for (int i = 0; i < 2; ++i) {
            int lin = i * 256 + t, r = lin >> 3, ch = lin & 7;
            int srcoff = r * 256 + c0 + ((ch ^ (r & 7)) << 3);
            gl_lds16(WkN + srcoff, &sK[lin * 8]);
            gl_lds16(WvN + srcoff, &sV[lin * 8]);
        }
#pragma unroll
        for (int j = 0; j < 4; ++j) {
            int s4 = j * 8 + sl;
            const float* src = fb + (long)(c0 + 2 * p) * 4096 + s0 + s4 * 4;
            float4 a = *(const float4*)src;
            float4 bq = *(const float4*)(src + 4096);
            char* base = (char*)sF + p * 4 + (s4 * 4) * 144;
            *(u32*)(base +   0) = pk2(a.x, bq.x);
            *(u32*)(base + 144) = pk2(a.y, bq.y);
            *(u32*)(base + 288) = pk2(a.z, bq.z);
            *(u32*)(base + 432) = pk2(a.w, bq.w);
        }
        __syncthreads();
#pragma unroll
        for (int kk = 0; kk < 2; ++kk) {
            bf16x8 ak[4], ff[2], bv[4];
#pragma unroll
            for (int mf = 0; mf < 4; ++mf) {
                int r = mf * 16 + lr;
                int ch = (kk * 4 + g) ^ (r & 7);
                ak[mf] = *(const bf16x8*)((const char*)sK + r * 128 + ch * 16);
            }
#pragma unroll
            for (int i = 0; i < 2; ++i) {
                int s = wid * 32 + i * 16 + lr;
                ff[i] = *(const bf16x8*)((const char*)sF + s * 144 + (kk * 4 + g) * 16);
            }
#pragma unroll
            for (int nf = 0; nf < 4; ++nf) {
                int r = nf * 16 + lr;
                int ch = (kk * 4 + g) ^ (r & 7);
                bv[nf] = *(const bf16x8*)((const char*)sV + r * 128 + ch * 16);
            }
#pragma unroll
            for (int mf = 0; mf < 4; ++mf)
#pragma unroll
                for (int i = 0; i < 2; ++i)
                    acc1[mf][i] = __builtin_amdgcn_mfma_f32_16x16x32_bf16(
                        ak[mf], ff[i], acc1[mf][i], 0, 0, 0);
#pragma unroll
            for (int i = 0; i < 2; ++i)
#pragma unroll
                for (int nf = 0; nf < 4; ++nf)
                    acc2[i][nf] = __builtin_amdgcn_mfma_f32_16x16x32_bf16(
                        ff[i], bv[nf], acc2[i][nf], 0, 0, 0);
        }
    }
    bf16* kbb = kb + (long)bn * 262144;
#pragma unroll
    for (int mf = 0; mf < 4; ++mf)
#pragma unroll
        for (int i = 0; i < 2; ++i)
#pragma unroll
            for (int e = 0; e < 4; ++e) {
                int dd = mf * 16 + g * 4 + e;
                int s  = s0 + wid * 32 + i * 16 + lr;
                kbb[(long)dd * 4096 + s] = __float2bfloat16(acc1[mf][i][e]);
            }
    bf16* vtb = vT + (long)bn * 262144;
#pragma unroll
    for (int i = 0; i < 2; ++i)
#pragma unroll
        for (int nf = 0; nf < 4; ++nf)
#pragma unroll
            for (int e = 0; e < 4; ++e) {
                int s = s0 + wid * 32 + i * 16 + g * 4 + e;
                int ec = nf * 16 + lr;
                vtb[(long)s * 64 + ec] = __float2bfloat16(acc2[i][nf][e]);
            }
}

// ---------------------------------------------------------------------------
// Unified bf16 MFMA GEMM (round-2 proven): Y[m][n] = sum_k A[m][k]*B[n][k]
// EPI: 2 = f32 out + bias + bf16 res; 3 = f32 out plain.
// ---------------------------------------------------------------------------
template<int BM, int BN, int EPI>
__global__ __launch_bounds__(256) void gemm_bt(
    const bf16* __restrict__ Ab, const bf16* __restrict__ Bb,
    void* __restrict__ Yb, const bf16* __restrict__ Rb,
    const float* __restrict__ bias,
    int K, int ldA, int ldB, int ldY, int bshift,
    long sAhi, long sAlo, long sBhi, long sBlo, long sYhi, long sYlo)
{
    constexpr int WM = BM / 2, WN = BN / 2;
    constexpr int MF = WM / 16, NF = WN / 16;
    __shared__ bf16 sA[BM * 64];
    __shared__ bf16 sB[BN * 64];

    const int t = threadIdx.x;
    const int lane = t & 63;
    const int wid = t >> 6;
    const int wm = wid >> 1, wn = wid & 1;
    const int g = lane >> 4, lr = lane & 15;

    const int bz = blockIdx.z;
    const long hi = bz >> bshift;
    const long lo = bz & ((1 << bshift) - 1);
    const bf16* A = Ab + hi * sAhi + lo * sAlo + (long)blockIdx.y * BM * ldA;
    const bf16* B = Bb + hi * sBhi + lo * sBlo + (long)blockIdx.x * BN * ldB;

    f32x4 acc[MF][NF];
#pragma unroll
    for (int mf = 0; mf < MF; ++mf)
#pragma unroll
        for (int nf = 0; nf < NF; ++nf) acc[mf][nf] = (f32x4){0.f, 0.f, 0.f, 0.f};

    for (int k0 = 0; k0 < K; k0 += 64) {
        __syncthreads();
#pragma unroll
        for (int i = 0; i < BM / 32; ++i) {
            int lin = i * 256 + t, r = lin >> 3, ch = lin & 7;
            gl_lds16(A + (long)r * ldA + k0 + ((ch ^ (r & 7)) << 3), &sA[lin * 8]);
        }
#pragma unroll
        for (int i = 0; i < BN / 32; ++i) {
            int lin = i * 256 + t, r = lin >> 3, ch = lin & 7;
            gl_lds16(B + (long)r * ldB + k0 + ((ch ^ (r & 7)) << 3), &sB[lin * 8]);
        }
        __syncthreads();
#pragma unroll
        for (int kk = 0; kk < 2; ++kk) {
            bf16x8 af[MF], bfr[NF];
#pragma unroll
            for (int mf = 0; mf < MF; ++mf) {
                int r = wm * WM + mf * 16 + lr;
                int ch = (kk * 4 + g) ^ (r & 7);
                af[mf] = *(const bf16x8*)((const char*)sA + r * 128 + ch * 16);
            }
#pragma unroll
            for (int nf = 0; nf < NF; ++nf) {
                int r = wn * WN + nf * 16 + lr;
                int ch = (kk * 4 + g) ^ (r & 7);
                bfr[nf] = *(const bf16x8*)((const char*)sB + r * 128 + ch * 16);
            }
#pragma unroll
            for (int mf = 0; mf < MF; ++mf)
#pragma unroll
                for (int nf = 0; nf < NF; ++nf)
                    acc[mf][nf] = __builtin_amdgcn_mfma_f32_16x16x32_bf16(
                        af[mf], bfr[nf], acc[mf][nf], 0, 0, 0);
        }
    }

    const long ybase = hi * sYhi + lo * sYlo;
    const int m0 = blockIdx.y * BM + wm * WM;
    const int n0 = blockIdx.x * BN + wn * WN;
#pragma unroll
    for (int mf = 0; mf < MF; ++mf)
#pragma unroll
        for (int nf = 0; nf < NF; ++nf)
#pragma unroll
            for (int e = 0; e < 4; ++e) {
                int m = m0 + mf * 16 + g * 4 + e;
                int n = n0 + nf * 16 + lr;
                long idx = ybase + (long)m * ldY + n;
                float v = acc[mf][nf][e];
                if (EPI == 2) v += __bfloat162float(Rb[idx]) + bias[m];
                ((float*)Yb)[idx] = v;
            }
}

// ---------------------------------------------------------------------------
// PV + residual from ch-major qch:
// Z[b][s][n*64+dd] = sum_e attnb[bn][dd][e]*vT[bn][s][e] + qch[b][n*64+dd][s]
// grid (32 s-tiles, 64 bn), block 256 (4 waves 2x2: WM=64 s, WN=32 dd).
// ---------------------------------------------------------------------------
__global__ __launch_bounds__(256) void pv2(
    const bf16* __restrict__ vT,    // [64][4096][64]
    const bf16* __restrict__ attnb, // [64][64][64]
    const bf16* __restrict__ qch,   // [16][256][4096]
    bf16* __restrict__ Z)           // [16][4096][256]
{
    __shared__ bf16 sVt[128 * 64];
    __shared__ bf16 sAt[64 * 64];
    const int t = threadIdx.x;
    const int lane = t & 63, wid = t >> 6;
    const int wm = wid >> 1, wn = wid & 1;
    const int g = lane >> 4, lr = lane & 15;
    const int s0 = blockIdx.x * 128;
    const int bn = blockIdx.y, b = bn >> 2, n = bn & 3;

#pragma unroll
    for (int i = 0; i < 4; ++i) {
        int lin = i * 256 + t, r = lin >> 3, ch = lin & 7;
        gl_lds16(vT + (long)bn * 262144 + (long)(s0 + r) * 64 + ((ch ^ (r & 7)) << 3),
                 &sVt[lin * 8]);
    }
#pragma unroll
    for (int i = 0; i < 2; ++i) {
        int lin = i * 256 + t, r = lin >> 3, ch = lin & 7;
        gl_lds16(attnb + (long)bn * 4096 + r * 64 + ((ch ^ (r & 7)) << 3), &sAt[lin * 8]);
    }
    __syncthreads();

    f32x4 acc[4][2];
#pragma unroll
    for (int i = 0; i < 4; ++i)
#pragma unroll
        for (int j = 0; j < 2; ++j) acc[i][j] = (f32x4){0.f, 0.f, 0.f, 0.f};

#pragma unroll
    for (int kk = 0; kk < 2; ++kk) {
        bf16x8 av[4], bt[2];
#pragma unroll
        for (int mf = 0; mf < 4; ++mf) {
            int r = wm * 64 + mf * 16 + lr;
            int ch = (kk * 4 + g) ^ (r & 7);
            av[mf] = *(const bf16x8*)((const char*)sVt + r * 128 + ch * 16);
        }
#pragma unroll
        for (int nf = 0; nf < 2; ++nf) {
            int r = wn * 32 + nf * 16 + lr;
            int ch = (kk * 4 + g) ^ (r & 7);
            bt[nf] = *(const bf16x8*)((const char*)sAt + r * 128 + ch * 16);
        }
#pragma unroll
        for (int mf = 0; mf < 4; ++mf)
#pragma unroll
            for (int nf = 0; nf < 2; ++nf)
                acc[mf][nf] = __builtin_amdgcn_mfma_f32_16x16x32_bf16(
                    av[mf], bt[nf], acc[mf][nf], 0, 0, 0);
    }

    bf16* Zb = Z + (long)b * 1048576;
    const bf16* qb = qch + (long)b * 1048576;
#pragma unroll
    for (int mf = 0; mf < 4; ++mf)
#pragma unroll
        for (int nf = 0; nf < 2; ++nf) {
            int c = n * 64 + wn * 32 + nf * 16 + lr;
            int sbase = s0 + wm * 64 + mf * 16 + g * 4;
            ushort4 qv = *(const ushort4*)(qb + (long)c * 4096 + sbase);
            u16 qa[4] = {qv.x, qv.y, qv.z, qv.w};
#pragma unroll
            for (int e = 0; e < 4; ++e) {
                float r2 = __uint_as_float((u32)qa[e] << 16);
                Zb[(long)(sbase + e) * 256 + c] =
                    __float2bfloat16(acc[mf][nf][e] + r2);
            }
        }
}

// ---------------------------------------------------------------------------
__global__ __launch_bounds__(256) void wconv(
    const float* __restrict__ a, const float* __restrict__ b,
    const float* __restrict__ c, const float* __restrict__ d,
    bf16* __restrict__ o)
{
    int i = blockIdx.x * 256 + threadIdx.x;
    int which = i >> 16, off = i & 65535;
    const float* s = (which == 0) ? a : (which == 1) ? b : (which == 2) ? c : d;
    o[i] = __float2bfloat16(s[off]);
}

__global__ __launch_bounds__(256) void normk(
    const bf16* __restrict__ qch, const bf16* __restrict__ kb,
    float* __restrict__ invq, float* __restrict__ invk)
{
    int row = blockIdx.x;
    const bf16* base = (row < 4096) ? qch + (long)row * 4096
                                    : kb + (long)(row - 4096) * 4096;
    int t = threadIdx.x;
    float s = 0.f;
#pragma unroll
    for (int h = 0; h < 2; ++h) {
        uint4 v = *(const uint4*)(base + h * 2048 + t * 8);
        u32 ws[4] = {v.x, v.y, v.z, v.w};
#pragma unroll
        for (int j = 0; j < 4; ++j) {
            float lo = __uint_as_float(ws[j] << 16);
            float hi2 = __uint_as_float(ws[j] & 0xffff0000u);
            s += lo * lo + hi2 * hi2;
        }
    }
    __shared__ float red[256];
    red[t] = s;
    __syncthreads();
    for (int off = 128; off > 0; off >>= 1) {
        if (t < off) red[t] += red[t + off];
        __syncthreads();
    }
    if (t == 0) {
        float inv = 1.0f / fmaxf(sqrtf(red[0]), 1e-12f);
        if (row < 4096) invq[row] = inv;
        else            invk[row - 4096] = inv;
    }
}

__global__ __launch_bounds__(256) void attn_finalize_kernel(
    const float* __restrict__ part,
    const float* __restrict__ invq, const float* __restrict__ invk,
    const float* __restrict__ rescale,
    bf16* __restrict__ attn_out)
{
    const int bn = blockIdx.x;
    const int n = bn & 3;
    const int t = threadIdx.x;
    const float rs = rescale[n];

    __shared__ float att[64][65];
    __shared__ float rmax[64], rsum[64];

    const float* pb = part + (size_t)bn * 4 * 4096;
#pragma unroll
    for (int p = 0; p < 16; ++p) {
        int lin = p * 256 + t;
        int dd = lin >> 6, e = lin & 63;
        float v = pb[lin] + pb[4096 + lin] + pb[8192 + lin] + pb[12288 + lin];
        v *= invk[bn * 64 + dd] * invq[bn * 64 + e] * rs;
        att[dd][e] = v;
    }
    __syncthreads();
    if (t < 64) {
        float m = -1e30f;
        for (int e = 0; e < 64; ++e) m = fmaxf(m, att[t][e]);
        float sm = 0.f;
        for (int e = 0; e < 64; ++e) sm += expf(att[t][e] - m);
        rmax[t] = m;
        rsum[t] = 1.0f / sm;
    }
    __syncthreads();
    bf16* ob = attn_out + (size_t)bn * 4096;
#pragma unroll
    for (int p = 0; p < 16; ++p) {
        int lin = p * 256 + t;
        int dd = lin >> 6, e = lin & 63;
        ob[lin] = __float2bfloat16(expf(att[dd][e] - rmax[dd]) * rsum[dd]);
    }
}

// ---------------------------------------------------------------------------
extern "C" void kernel_launch(void* const* d_in, const int* in_sizes, int n_in,
                              void* d_out, int out_size, void* d_ws, size_t ws_size,
                              hipStream_t stream) {
    const float* x       = (const float*)d_in[0];
    const float* fmaps   = (const float*)d_in[1];
    const float* Wq      = (const float*)d_in[2];
    const float* Wk      = (const float*)d_in[3];
    const float* Wv      = (const float*)d_in[4];
    const float* rescale = (const float*)d_in[5];
    const float* Wffn    = (const float*)d_in[6];
    const float* bffn    = (const float*)d_in[7];
    float* out = (float*)d_out;

    char* w = (char*)d_ws;
    bf16* kbuf  = (bf16*)(w + 0);             // 33.55 MB; reused as Z
    bf16* Z     = kbuf;
    bf16* vT    = (bf16*)(w + 33554432L);
    bf16* qch   = (bf16*)(w + 67108864L);
    float* part = (float*)(w + 100663296L);   // 4.19 MB
    bf16* attnb = (bf16*)(w + 104857600L);
    float* invq = (float*)(w + 105381888L);
    float* invk = (float*)(w + 105398272L);
    bf16* Wq_b  = (bf16*)(w + 105414656L);
    bf16* Wk_b  = Wq_b + 65536;
    bf16* Wv_b  = Wq_b + 131072;
    bf16* Wf_b  = Wq_b + 196608;

    dim3 blk(256);
    const long BS = 1048576;

    // 1. weights -> bf16
    wconv<<<dim3(1024), blk, 0, stream>>>(Wq, Wk, Wv, Wffn, Wq_b);
    // 2. K/V projections, fmaps read once
    kvproj<<<dim3(32, 64), blk, 0, stream>>>(fmaps, Wk_b, Wv_b, kbuf, vT);
    // 3. Q projection
    qproj<<<dim3(32, 2, 16), blk, 0, stream>>>(x, Wq_b, qch);
    // 4. inverse L2 norms
    normk<<<dim3(8192), blk, 0, stream>>>(qch, kbuf, invq, invk);
    // 5. QK^T partials over 4 s-chunks
    gemm_bt<64, 64, 3><<<dim3(1, 1, 256), blk, 0, stream>>>(
        kbuf, qch, part, nullptr, nullptr,
        1024, 4096, 4096, 64, 2,
        262144, 1024, 262144, 1024, 16384, 4096);
    // 6. finalize: scale + softmax -> attn bf16
    attn_finalize_kernel<<<dim3(64), blk, 0, stream>>>(part, invq, invk, rescale, attnb);
    // 7. PV + q residual -> Z (overlays kbuf)
    pv2<<<dim3(32, 64), blk, 0, stream>>>(vT, attnb, qch, Z);
    // 8. FFN + bffn + qch residual -> out f32
    gemm_bt<128, 128, 2><<<dim3(32, 2, 16), blk, 0, stream>>>(
        Wf_b, Z, out, qch, bffn,
        256, 256, 256, 4096, 0,
        0, 0, BS, 0, BS, 0);
}

// Round 4
// 200.897 us; speedup vs baseline: 2.7242x; 1.0018x over previous
//
#include <hip/hip_runtime.h>
#include <hip/hip_bf16.h>
#include <cmath>

using bf16 = __hip_bfloat16;
typedef __attribute__((ext_vector_type(4))) float  f32x4;
typedef __attribute__((ext_vector_type(8))) short  bf16x8;
typedef unsigned int u32;
typedef unsigned short u16;

// async global->LDS, 16B per lane
__device__ __forceinline__ void gl_lds16(const bf16* g, bf16* l) {
    __builtin_amdgcn_global_load_lds(
        (const __attribute__((address_space(1))) u32*)g,
        (__attribute__((address_space(3))) u32*)l, 16, 0, 0);
}

__device__ __forceinline__ u32 pk2(float a, float b) {
    bf16 ha = __float2bfloat16(a), hb = __float2bfloat16(b);
    return (u32)*(u16*)&ha | ((u32)*(u16*)&hb << 16);
}
__device__ __forceinline__ float b2f(u16 v) {
    return __uint_as_float((u32)v << 16);
}

// ---------------------------------------------------------------------------
// Q projection, fused transpose-convert of x. (round-3 proven)
// qch[b][o][s] = sum_c Wq[o][c] * x[b][c][s]
// ---------------------------------------------------------------------------
__global__ __launch_bounds__(256) void qproj(
    const float* __restrict__ x,   // [16][256][4096]
    const bf16* __restrict__ Wq,   // [256][256]
    bf16* __restrict__ qch)        // [16][256][4096]
{
    __shared__ bf16 sW[128 * 64];
    __shared__ bf16 sX[128 * 72];
    const int t = threadIdx.x;
    const int lane = t & 63, wid = t >> 6;
    const int wm = wid >> 1, wn = wid & 1;
    const int g = lane >> 4, lr = lane & 15;
    const int s0 = blockIdx.x * 128;
    const int o0 = blockIdx.y * 128;
    const float* xb = x + (long)blockIdx.z * 1048576;

    f32x4 acc[4][4];
#pragma unroll
    for (int i = 0; i < 4; ++i)
#pragma unroll
        for (int j = 0; j < 4; ++j) acc[i][j] = (f32x4){0.f, 0.f, 0.f, 0.f};

    const int p  = t & 31;
    const int sl = t >> 5;

    for (int c0 = 0; c0 < 256; c0 += 64) {
        __syncthreads();
#pragma unroll
        for (int i = 0; i < 4; ++i) {
            int lin = i * 256 + t, r = lin >> 3, ch = lin & 7;
            gl_lds16(Wq + (long)(o0 + r) * 256 + c0 + ((ch ^ (r & 7)) << 3), &sW[lin * 8]);
        }
#pragma unroll
        for (int j = 0; j < 4; ++j) {
            int s4 = j * 8 + sl;
            const float* src = xb + (long)(c0 + 2 * p) * 4096 + s0 + s4 * 4;
            float4 a = *(const float4*)src;
            float4 bq = *(const float4*)(src + 4096);
            char* base = (char*)sX + p * 4 + (s4 * 4) * 144;
            *(u32*)(base +   0) = pk2(a.x, bq.x);
            *(u32*)(base + 144) = pk2(a.y, bq.y);
            *(u32*)(base + 288) = pk2(a.z, bq.z);
            *(u32*)(base + 432) = pk2(a.w, bq.w);
        }
        __syncthreads();
#pragma unroll
        for (int kk = 0; kk < 2; ++kk) {
            bf16x8 aw[4], fx[4];
#pragma unroll
            for (int mf = 0; mf < 4; ++mf) {
                int r = wm * 64 + mf * 16 + lr;
                int ch = (kk * 4 + g) ^ (r & 7);
                aw[mf] = *(const bf16x8*)((const char*)sW + r * 128 + ch * 16);
            }
#pragma unroll
            for (int nf = 0; nf < 4; ++nf) {
                int s = wn * 64 + nf * 16 + lr;
                fx[nf] = *(const bf16x8*)((const char*)sX + s * 144 + (kk * 4 + g) * 16);
            }
#pragma unroll
            for (int mf = 0; mf < 4; ++mf)
#pragma unroll
                for (int nf = 0; nf < 4; ++nf)
                    acc[mf][nf] = __builtin_amdgcn_mfma_f32_16x16x32_bf16(
                        aw[mf], fx[nf], acc[mf][nf], 0, 0, 0);
        }
    }
    bf16* qb = qch + (long)blockIdx.z * 1048576;
#pragma unroll
    for (int mf = 0; mf < 4; ++mf)
#pragma unroll
        for (int nf = 0; nf < 4; ++nf)
#pragma unroll
            for (int e = 0; e < 4; ++e) {
                int o = o0 + wm * 64 + mf * 16 + g * 4 + e;
                int s = s0 + wn * 64 + nf * 16 + lr;
                qb[(long)o * 4096 + s] = __float2bfloat16(acc[mf][nf][e]);
            }
}

// ---------------------------------------------------------------------------
// K+V projection, fused transpose-convert of fmaps. (round-3 proven)
// ---------------------------------------------------------------------------
__global__ __launch_bounds__(256) void kvproj(
    const float* __restrict__ fm,  // [64][256][4096]
    const bf16* __restrict__ Wk,   // [4][64][256]
    const bf16* __restrict__ Wv,   // [4][64][256]
    bf16* __restrict__ kb,         // [64][64][4096]
    bf16* __restrict__ vT)         // [64][4096][64]
{
    __shared__ bf16 sF[128 * 72];
    __shared__ bf16 sK[64 * 64];
    __shared__ bf16 sV[64 * 64];
    const int t = threadIdx.x;
    const int lane = t & 63, wid = t >> 6;
    const int g = lane >> 4, lr = lane & 15;
    const int s0 = blockIdx.x * 128;
    const int bn = blockIdx.y, n = bn & 3;
    const float* fb = fm + (long)bn * 1048576;
    const bf16* WkN = Wk + (long)n * 16384;
    const bf16* WvN = Wv + (long)n * 16384;

    f32x4 acc1[4][2];
    f32x4 acc2[2][4];
#pragma unroll
    for (int i = 0; i < 4; ++i)
#pragma unroll
        for (int j = 0; j < 2; ++j) {
            acc1[i][j] = (f32x4){0.f, 0.f, 0.f, 0.f};
            acc2[j][i] = (f32x4){0.f, 0.f, 0.f, 0.f};
        }

    const int p  = t & 31;
    const int sl = t >> 5;

    for (int c0 = 0; c0 < 256; c0 += 64) {
        __syncthreads();
#pragma unroll
        for (int i = 0; i < 2; ++i) {
            int lin = i * 256 + t, r = lin >> 3, ch = lin & 7;
            int srcoff = r * 256 + c0 + ((ch ^ (r & 7)) << 3);
            gl_lds16(WkN + srcoff, &sK[lin * 8]);
            gl_lds16(WvN + srcoff, &sV[lin * 8]);
        }
#pragma unroll
        for (int j = 0; j < 4; ++j) {
            int s4 = j * 8 + sl;
            const float* src = fb + (long)(c0 + 2 * p) * 4096 + s0 + s4 * 4;
            float4 a = *(const float4*)src;
            float4 bq = *(const float4*)(src + 4096);
            char* base = (char*)sF + p * 4 + (s4 * 4) * 144;
            *(u32*)(base +   0) = pk2(a.x, bq.x);
            *(u32*)(base + 144) = pk2(a.y, bq.y);
            *(u32*)(base + 288) = pk2(a.z, bq.z);
            *(u32*)(base + 432) = pk2(a.w, bq.w);
        }
        __syncthreads();
#pragma unroll
        for (int kk = 0; kk < 2; ++kk) {
            bf16x8 ak[4], ff[2], bv[4];
#pragma unroll
            for (int mf = 0; mf < 4; ++mf) {
                int r = mf * 16 + lr;
                int ch = (kk * 4 + g) ^ (r & 7);
                ak[mf] = *(const bf16x8*)((const char*)sK + r * 128 + ch * 16);
            }
#pragma unroll
            for (int i = 0; i < 2; ++i) {
                int s = wid * 32 + i * 16 + lr;
                ff[i] = *(const bf16x8*)((const char*)sF + s * 144 + (kk * 4 + g) * 16);
            }
#pragma unroll
            for (int nf = 0; nf < 4; ++nf) {
                int r = nf * 16 + lr;
                int ch = (kk * 4 + g) ^ (r & 7);
                bv[nf] = *(const bf16x8*)((const char*)sV + r * 128 + ch * 16);
            }
#pragma unroll
            for (int mf = 0; mf < 4; ++mf)
#pragma unroll
                for (int i = 0; i < 2; ++i)
                    acc1[mf][i] = __builtin_amdgcn_mfma_f32_16x16x32_bf16(
                        ak[mf], ff[i], acc1[mf][i], 0, 0, 0);
#pragma unroll
            for (int i = 0; i < 2; ++i)
#pragma unroll
                for (int nf = 0; nf < 4; ++nf)
                    acc2[i][nf] = __builtin_amdgcn_mfma_f32_16x16x32_bf16(
                        ff[i], bv[nf], acc2[i][nf], 0, 0, 0);
        }
    }
    bf16* kbb = kb + (long)bn * 262144;
#pragma unroll
    for (int mf = 0; mf < 4; ++mf)
#pragma unroll
        for (int i = 0; i < 2; ++i)
#pragma unroll
            for (int e = 0; e < 4; ++e) {
                int dd = mf * 16 + g * 4 + e;
                int s  = s0 + wid * 32 + i * 16 + lr;
                kbb[(long)dd * 4096 + s] = __float2bfloat16(acc1[mf][i][e]);
            }
    bf16* vtb = vT + (long)bn * 262144;
#pragma unroll
    for (int i = 0; i < 2; ++i)
#pragma unroll
        for (int nf = 0; nf < 4; ++nf)
#pragma unroll
            for (int e = 0; e < 4; ++e) {
                int s = s0 + wid * 32 + i * 16 + g * 4 + e;
                int ec = nf * 16 + lr;
                vtb[(long)s * 64 + ec] = __float2bfloat16(acc2[i][nf][e]);
            }
}

// ---------------------------------------------------------------------------
// QK^T partial + fused row sum-of-squares.
// part[(bn*4+ch)][dd][e] = sum_{s in chunk} k[bn][dd][s]*q[bn][e][s]
// atomicAdd sumk[bn*64+dd] += sumsq(k chunk), sumq likewise.
// grid (4, 64), block 256 (4 waves 2x2, wave 32x32).
// ---------------------------------------------------------------------------
__global__ __launch_bounds__(256) void qk_sum(
    const bf16* __restrict__ kb,   // [64][64][4096]
    const bf16* __restrict__ qch,  // [16][256][4096] == [64][64][4096] per bn
    float* __restrict__ part,      // [64][4][64][64]
    float* __restrict__ sumq, float* __restrict__ sumk)
{
    __shared__ bf16 sA[64 * 64];
    __shared__ bf16 sB[64 * 64];
    const int t = threadIdx.x;
    const int lane = t & 63, wid = t >> 6;
    const int wm = wid >> 1, wn = wid & 1;
    const int g = lane >> 4, lr = lane & 15;
    const int ch_ = blockIdx.x;    // s-chunk 0..3
    const int bn = blockIdx.y;
    const bf16* kbase = kb + (long)bn * 262144;
    const bf16* qbase = qch + (long)bn * 262144;

    const int srow = t >> 1;       // 0..127 (64 k rows + 64 q rows)
    const int shalf = t & 1;

    f32x4 acc[2][2];
#pragma unroll
    for (int i = 0; i < 2; ++i)
#pragma unroll
        for (int j = 0; j < 2; ++j) acc[i][j] = (f32x4){0.f, 0.f, 0.f, 0.f};
    float ss = 0.f;

    for (int it = 0; it < 16; ++it) {
        int k0 = ch_ * 1024 + it * 64;
        __syncthreads();
#pragma unroll
        for (int i = 0; i < 2; ++i) {
            int lin = i * 256 + t, r = lin >> 3, c = lin & 7;
            gl_lds16(kbase + (long)r * 4096 + k0 + ((c ^ (r & 7)) << 3), &sA[lin * 8]);
            gl_lds16(qbase + (long)r * 4096 + k0 + ((c ^ (r & 7)) << 3), &sB[lin * 8]);
        }
        __syncthreads();
#pragma unroll
        for (int kk = 0; kk < 2; ++kk) {
            bf16x8 af[2], bf[2];
#pragma unroll
            for (int mf = 0; mf < 2; ++mf) {
                int r = wm * 32 + mf * 16 + lr;
                af[mf] = *(const bf16x8*)((const char*)sA + r * 128 + (((kk * 4 + g) ^ (r & 7)) << 4));
            }
#pragma unroll
            for (int nf = 0; nf < 2; ++nf) {
                int r = wn * 32 + nf * 16 + lr;
                bf[nf] = *(const bf16x8*)((const char*)sB + r * 128 + (((kk * 4 + g) ^ (r & 7)) << 4));
            }
#pragma unroll
            for (int mf = 0; mf < 2; ++mf)
#pragma unroll
                for (int nf = 0; nf < 2; ++nf)
                    acc[mf][nf] = __builtin_amdgcn_mfma_f32_16x16x32_bf16(
                        af[mf], bf[nf], acc[mf][nf], 0, 0, 0);
        }
        // fused sumsq: 2 threads per row read 4 chunks each
        {
            const char* base = (srow < 64) ? (const char*)sA + srow * 128
                                           : (const char*)sB + (srow - 64) * 128;
            int r7 = srow & 7;
#pragma unroll
            for (int j = 0; j < 4; ++j) {
                bf16x8 v = *(const bf16x8*)(base + (((shalf * 4 + j) ^ r7) << 4));
#pragma unroll
                for (int e = 0; e < 8; ++e) {
                    float f = b2f((u16)v[e]);
                    ss += f * f;
                }
            }
        }
    }
    // combine the two half-row partials and atomically accumulate
    ss += __shfl_xor(ss, 1);
    if (shalf == 0) {
        if (srow < 64) atomicAdd(&sumk[bn * 64 + srow], ss);
        else           atomicAdd(&sumq[bn * 64 + srow - 64], ss);
    }
    float* pp = part + ((long)bn * 4 + ch_) * 4096;
#pragma unroll
    for (int mf = 0; mf < 2; ++mf)
#pragma unroll
        for (int nf = 0; nf < 2; ++nf)
#pragma unroll
            for (int e = 0; e < 4; ++e) {
                int m = wm * 32 + mf * 16 + g * 4 + e;
                int nn = wn * 32 + nf * 16 + lr;
                pp[m * 64 + nn] = acc[mf][nf][e];
            }
}

// ---------------------------------------------------------------------------
// finalize: sum partials, rsqrt norms, scale, softmax -> bf16
// ---------------------------------------------------------------------------
__global__ __launch_bounds__(256) void attn_finalize_kernel(
    const float* __restrict__ part,
    const float* __restrict__ sumq, const float* __restrict__ sumk,
    const float* __restrict__ rescale,
    bf16* __restrict__ attn_out)
{
    const int bn = blockIdx.x;
    const int n = bn & 3;
    const int t = threadIdx.x;
    const float rs = rescale[n];

    __shared__ float att[64][65];
    __shared__ float rmax[64], rsum[64];
    __shared__ float iq[64], ik[64];

    if (t < 64)        ik[t]      = 1.f / fmaxf(sqrtf(sumk[bn * 64 + t]), 1e-12f);
    else if (t < 128)  iq[t - 64] = 1.f / fmaxf(sqrtf(sumq[bn * 64 + t - 64]), 1e-12f);
    __syncthreads();

    const float* pb = part + (size_t)bn * 4 * 4096;
#pragma unroll
    for (int p = 0; p < 16; ++p) {
        int lin = p * 256 + t;
        int dd = lin >> 6, e = lin & 63;
        float v = pb[lin] + pb[4096 + lin] + pb[8192 + lin] + pb[12288 + lin];
        v *= ik[dd] * iq[e] * rs;
        att[dd][e] = v;
    }
    __syncthreads();
    if (t < 64) {
        float m = -1e30f;
        for (int e = 0; e < 64; ++e) m = fmaxf(m, att[t][e]);
        float sm = 0.f;
        for (int e = 0; e < 64; ++e) sm += expf(att[t][e] - m);
        rmax[t] = m;
        rsum[t] = 1.0f / sm;
    }
    __syncthreads();
    bf16* ob = attn_out + (size_t)bn * 4096;
#pragma unroll
    for (int p = 0; p < 16; ++p) {
        int lin = p * 256 + t;
        int dd = lin >> 6, e = lin & 63;
        ob[lin] = __float2bfloat16(expf(att[dd][e] - rmax[dd]) * rsum[dd]);
    }
}

// ---------------------------------------------------------------------------
// Fused PV + FFN:
//  per (s-tile, b): loop n=0..3:
//    Zn[s][i] = sum_e attn[bn][i][e]*vT[bn][s][e] + qch[b][n*64+i][s] (LDS)
//    accF[c][s] += Wffn[c][n*64+i] * Zn[s][i]
//  epilogue: out[b][c][s] = accF + bffn[c] + qch[b][c][s]
// grid (32 s-tiles, 16 b), block 256, 4 waves: wave wid owns c-range wid*64
// (FFN) and s-range wid*32 (PV).
// ---------------------------------------------------------------------------
__global__ __launch_bounds__(256) void pvffn(
    const bf16* __restrict__ vT,    // [64][4096][64]
    const bf16* __restrict__ attnb, // [64][64][64]
    const bf16* __restrict__ qch,   // [16][256][4096]
    const bf16* __restrict__ Wf,    // [256][256]
    const float* __restrict__ bffn, // [256]
    float* __restrict__ out)        // [16][256][4096]
{
    __shared__ bf16 bufX[256 * 64]; // 32 KB: {vT 16K + attn 16K-region} / Wf
    __shared__ bf16 Zs[128 * 64];   // 16 KB, XOR-swizzled rows
    const int t = threadIdx.x;
    const int lane = t & 63, wid = t >> 6;
    const int g = lane >> 4, lr = lane & 15;
    const int s0 = blockIdx.x * 128;
    const int b = blockIdx.y;

    f32x4 accF[4][8];
#pragma unroll
    for (int i = 0; i < 4; ++i)
#pragma unroll
        for (int j = 0; j < 8; ++j) accF[i][j] = (f32x4){0.f, 0.f, 0.f, 0.f};

    for (int n = 0; n < 4; ++n) {
        const int bn = b * 4 + n;
        __syncthreads();   // prev FFN finished reading bufX & Zs
        // stage vT tile (128 rows x 64) into bufX[0:8192]
#pragma unroll
        for (int i = 0; i < 4; ++i) {
            int lin = i * 256 + t, r = lin >> 3, c = lin & 7;
            gl_lds16(vT + (long)bn * 262144 + (long)(s0 + r) * 64 + ((c ^ (r & 7)) << 3),
                     &bufX[lin * 8]);
        }
        // stage attn (64 rows x 64) into bufX[8192:12288]
#pragma unroll
        for (int i = 0; i < 2; ++i) {
            int lin = i * 256 + t, r = lin >> 3, c = lin & 7;
            gl_lds16(attnb + (long)bn * 4096 + r * 64 + ((c ^ (r & 7)) << 3),
                     &bufX[8192 + lin * 8]);
        }
        __syncthreads();
        // PV: wave wid owns s-rows wid*32..+31; acc [2 s-frag][4 dd-frag]
        f32x4 accP[2][4];
#pragma unroll
        for (int i = 0; i < 2; ++i)
#pragma unroll
            for (int j = 0; j < 4; ++j) accP[i][j] = (f32x4){0.f, 0.f, 0.f, 0.f};
#pragma unroll
        for (int kk = 0; kk < 2; ++kk) {
            bf16x8 av[2], at[4];
#pragma unroll
            for (int mf = 0; mf < 2; ++mf) {
                int r = wid * 32 + mf * 16 + lr;
                av[mf] = *(const bf16x8*)((const char*)bufX + r * 128 + (((kk * 4 + g) ^ (r & 7)) << 4));
            }
#pragma unroll
            for (int nf = 0; nf < 4; ++nf) {
                int r = nf * 16 + lr;
                at[nf] = *(const bf16x8*)((const char*)bufX + 16384 + r * 128 + (((kk * 4 + g) ^ (r & 7)) << 4));
            }
#pragma unroll
            for (int mf = 0; mf < 2; ++mf)
#pragma unroll
                for (int nf = 0; nf < 4; ++nf)
                    accP[mf][nf] = __builtin_amdgcn_mfma_f32_16x16x32_bf16(
                        av[mf], at[nf], accP[mf][nf], 0, 0, 0);
        }
        // write Z slice (+ q residual) into swizzled Zs
#pragma unroll
        for (int mf = 0; mf < 2; ++mf)
#pragma unroll
            for (int nf = 0; nf < 4; ++nf) {
                int slb = wid * 32 + mf * 16 + g * 4;
                int il = nf * 16 + lr;
                ushort4 qv = *(const ushort4*)(qch + ((long)b * 256 + n * 64 + il) * 4096 + s0 + slb);
                u16 qa[4] = {qv.x, qv.y, qv.z, qv.w};
#pragma unroll
                for (int e = 0; e < 4; ++e) {
                    int sl = slb + e;
                    float v = accP[mf][nf][e] + b2f(qa[e]);
                    bf16 hv = __float2bfloat16(v);
                    int byte = sl * 128 + ((((il >> 3) ^ (sl & 7))) << 4) + (il & 7) * 2;
                    *(u16*)((char*)Zs + byte) = *(u16*)&hv;
                }
            }
        __syncthreads();   // Zs ready; bufX reads (PV) complete
        // stage Wf chunk [256 c][64 i] into bufX
#pragma unroll
        for (int i = 0; i < 8; ++i) {
            int lin = i * 256 + t, r = lin >> 3, c = lin & 7;
            gl_lds16(Wf + (long)r * 256 + n * 64 + ((c ^ (r & 7)) << 3), &bufX[lin * 8]);
        }
        __syncthreads();
        // FFN partial: wave wid owns c-rows wid*64..+63; all 128 s
#pragma unroll
        for (int kk = 0; kk < 2; ++kk) {
            bf16x8 aw[4], bz[8];
#pragma unroll
            for (int mf = 0; mf < 4; ++mf) {
                int r = wid * 64 + mf * 16 + lr;
                aw[mf] = *(const bf16x8*)((const char*)bufX + r * 128 + (((kk * 4 + g) ^ (r & 7)) << 4));
            }
#pragma unroll
            for (int nf = 0; nf < 8; ++nf) {
                int sl = nf * 16 + lr;
                bz[nf] = *(const bf16x8*)((const char*)Zs + sl * 128 + (((kk * 4 + g) ^ (sl & 7)) << 4));
            }
#pragma unroll
            for (int mf = 0; mf < 4; ++mf)
#pragma unroll
                for (int nf = 0; nf < 8; ++nf)
                    accF[mf][nf] = __builtin_amdgcn_mfma_f32_16x16x32_bf16(
                        aw[mf], bz[nf], accF[mf][nf], 0, 0, 0);
        }
    }
    // epilogue: + bffn + qch residual -> f32 out
    float* ob = out + (long)b * 1048576;
    const bf16* qb = qch + (long)b * 1048576;
#pragma unroll
    for (int mf = 0; mf < 4; ++mf)
#pragma unroll
        for (int e = 0; e < 4; ++e) {
            int c = wid * 64 + mf * 16 + g * 4 + e;
            float bv = bffn[c];
#pragma unroll
            for (int nf = 0; nf < 8; ++nf) {
                int s = s0 + nf * 16 + lr;
                long idx = (long)c * 4096 + s;
                ob[idx] = accF[mf][nf][e] + bv + b2f(*(const u16*)(qb + idx));
            }
        }
}

// ---------------------------------------------------------------------------
__global__ __launch_bounds__(256) void wconv(
    const float* __restrict__ a, const float* __restrict__ b,
    const float* __restrict__ c, const float* __restrict__ d,
    bf16* __restrict__ o)
{
    int i = blockIdx.x * 256 + threadIdx.x;
    int which = i >> 16, off = i & 65535;
    const float* s = (which == 0) ? a : (which == 1) ? b : (which == 2) ? c : d;
    o[i] = __float2bfloat16(s[off]);
}

// ---------------------------------------------------------------------------
extern "C" void kernel_launch(void* const* d_in, const int* in_sizes, int n_in,
                              void* d_out, int out_size, void* d_ws, size_t ws_size,
                              hipStream_t stream) {
    const float* x       = (const float*)d_in[0];
    const float* fmaps   = (const float*)d_in[1];
    const float* Wq      = (const float*)d_in[2];
    const float* Wk      = (const float*)d_in[3];
    const float* Wv      = (const float*)d_in[4];
    const float* rescale = (const float*)d_in[5];
    const float* Wffn    = (const float*)d_in[6];
    const float* bffn    = (const float*)d_in[7];
    float* out = (float*)d_out;

    char* w = (char*)d_ws;
    bf16* kbuf  = (bf16*)(w + 0);             // 33.55 MB
    bf16* vT    = (bf16*)(w + 33554432L);     // 33.55 MB
    bf16* qch   = (bf16*)(w + 67108864L);     // 33.55 MB
    float* part = (float*)(w + 100663296L);   // 4.19 MB
    bf16* attnb = (bf16*)(w + 104857600L);    // 512 KB
    float* sumq = (float*)(w + 105381888L);   // 16 KB
    float* sumk = (float*)(w + 105398272L);   // 16 KB
    bf16* Wq_b  = (bf16*)(w + 105414656L);
    bf16* Wk_b  = Wq_b + 65536;
    bf16* Wv_b  = Wq_b + 131072;
    bf16* Wf_b  = Wq_b + 196608;

    dim3 blk(256);

    // 0. zero the sumsq accumulators (poisoned once, never re-poisoned)
    hipMemsetAsync(sumq, 0, 32768, stream);
    // 1. weights -> bf16
    wconv<<<dim3(1024), blk, 0, stream>>>(Wq, Wk, Wv, Wffn, Wq_b);
    // 2. K/V projections, fmaps read once
    kvproj<<<dim3(32, 64), blk, 0, stream>>>(fmaps, Wk_b, Wv_b, kbuf, vT);
    // 3. Q projection
    qproj<<<dim3(32, 2, 16), blk, 0, stream>>>(x, Wq_b, qch);
    // 4. QK^T partials + fused row sumsq
    qk_sum<<<dim3(4, 64), blk, 0, stream>>>(kbuf, qch, part, sumq, sumk);
    // 5. finalize: rsqrt + scale + softmax -> attn bf16
    attn_finalize_kernel<<<dim3(64), blk, 0, stream>>>(part, sumq, sumk, rescale, attnb);
    // 6. fused PV + FFN -> out f32
    pvffn<<<dim3(32, 16), blk, 0, stream>>>(vT, attnb, qch, Wf_b, bffn, out);
}

// Round 5
// 194.163 us; speedup vs baseline: 2.8187x; 1.0347x over previous
//
#include <hip/hip_runtime.h>
#include <hip/hip_bf16.h>
#include <cmath>

using bf16 = __hip_bfloat16;
typedef __attribute__((ext_vector_type(4))) float  f32x4;
typedef __attribute__((ext_vector_type(8))) short  bf16x8;
typedef unsigned int u32;
typedef unsigned short u16;

// async global->LDS, 16B per lane
__device__ __forceinline__ void gl_lds16(const bf16* g, bf16* l) {
    __builtin_amdgcn_global_load_lds(
        (const __attribute__((address_space(1))) u32*)g,
        (__attribute__((address_space(3))) u32*)l, 16, 0, 0);
}

__device__ __forceinline__ u32 pk2(float a, float b) {
    bf16 ha = __float2bfloat16(a), hb = __float2bfloat16(b);
    return (u32)*(u16*)&ha | ((u32)*(u16*)&hb << 16);
}
__device__ __forceinline__ float b2f(u16 v) {
    return __uint_as_float((u32)v << 16);
}

// ---------------------------------------------------------------------------
// Q projection, fused transpose-convert of x, double-buffered.
// qch[b][o][s] = sum_c Wq[o][c] * x[b][c][s]
// grid (32 s-tiles, 2 o-tiles, 16 b), block 256 (4 waves 2x2).
// ---------------------------------------------------------------------------
__global__ __launch_bounds__(256) void qproj(
    const float* __restrict__ x,   // [16][256][4096]
    const bf16* __restrict__ Wq,   // [256][256]
    bf16* __restrict__ qch)        // [16][256][4096]
{
    __shared__ bf16 sW[2][128 * 64];
    __shared__ bf16 sX[2][128 * 72];
    const int t = threadIdx.x;
    const int lane = t & 63, wid = t >> 6;
    const int wm = wid >> 1, wn = wid & 1;
    const int g = lane >> 4, lr = lane & 15;
    const int s0 = blockIdx.x * 128;
    const int o0 = blockIdx.y * 128;
    const float* xb = x + (long)blockIdx.z * 1048576;

    f32x4 acc[4][4];
#pragma unroll
    for (int i = 0; i < 4; ++i)
#pragma unroll
        for (int j = 0; j < 4; ++j) acc[i][j] = (f32x4){0.f, 0.f, 0.f, 0.f};

    const int p  = t & 31;
    const int sl = t >> 5;

    // prologue: stage c0=0 into buf 0
    {
#pragma unroll
        for (int i = 0; i < 4; ++i) {
            int lin = i * 256 + t, r = lin >> 3, ch = lin & 7;
            gl_lds16(Wq + (long)(o0 + r) * 256 + ((ch ^ (r & 7)) << 3), &sW[0][lin * 8]);
        }
        float4 ra[4], rb[4];
#pragma unroll
        for (int j = 0; j < 4; ++j) {
            const float* src = xb + (long)(2 * p) * 4096 + s0 + (j * 8 + sl) * 4;
            ra[j] = *(const float4*)src;
            rb[j] = *(const float4*)(src + 4096);
        }
#pragma unroll
        for (int j = 0; j < 4; ++j) {
            char* base = (char*)&sX[0][0] + p * 4 + ((j * 8 + sl) * 4) * 144;
            *(u32*)(base +   0) = pk2(ra[j].x, rb[j].x);
            *(u32*)(base + 144) = pk2(ra[j].y, rb[j].y);
            *(u32*)(base + 288) = pk2(ra[j].z, rb[j].z);
            *(u32*)(base + 432) = pk2(ra[j].w, rb[j].w);
        }
        __syncthreads();
    }

    int cur = 0;
    for (int it = 0; it < 4; ++it) {
        const int c0n = (it + 1) * 64;
        float4 ra[4], rb[4];
        if (it < 3) {
#pragma unroll
            for (int i = 0; i < 4; ++i) {
                int lin = i * 256 + t, r = lin >> 3, ch = lin & 7;
                gl_lds16(Wq + (long)(o0 + r) * 256 + c0n + ((ch ^ (r & 7)) << 3),
                         &sW[cur ^ 1][lin * 8]);
            }
#pragma unroll
            for (int j = 0; j < 4; ++j) {
                const float* src = xb + (long)(c0n + 2 * p) * 4096 + s0 + (j * 8 + sl) * 4;
                ra[j] = *(const float4*)src;
                rb[j] = *(const float4*)(src + 4096);
            }
        }
        const char* wbase = (const char*)&sW[cur][0];
        const char* xbase = (const char*)&sX[cur][0];
#pragma unroll
        for (int kk = 0; kk < 2; ++kk) {
            bf16x8 aw[4], fx[4];
#pragma unroll
            for (int mf = 0; mf < 4; ++mf) {
                int r = wm * 64 + mf * 16 + lr;
                aw[mf] = *(const bf16x8*)(wbase + r * 128 + (((kk * 4 + g) ^ (r & 7)) << 4));
            }
#pragma unroll
            for (int nf = 0; nf < 4; ++nf) {
                int s = wn * 64 + nf * 16 + lr;
                fx[nf] = *(const bf16x8*)(xbase + s * 144 + (kk * 4 + g) * 16);
            }
#pragma unroll
            for (int mf = 0; mf < 4; ++mf)
#pragma unroll
                for (int nf = 0; nf < 4; ++nf)
                    acc[mf][nf] = __builtin_amdgcn_mfma_f32_16x16x32_bf16(
                        aw[mf], fx[nf], acc[mf][nf], 0, 0, 0);
        }
        if (it < 3) {
#pragma unroll
            for (int j = 0; j < 4; ++j) {
                char* base = (char*)&sX[cur ^ 1][0] + p * 4 + ((j * 8 + sl) * 4) * 144;
                *(u32*)(base +   0) = pk2(ra[j].x, rb[j].x);
                *(u32*)(base + 144) = pk2(ra[j].y, rb[j].y);
                *(u32*)(base + 288) = pk2(ra[j].z, rb[j].z);
                *(u32*)(base + 432) = pk2(ra[j].w, rb[j].w);
            }
            __syncthreads();
            cur ^= 1;
        }
    }

    bf16* qb = qch + (long)blockIdx.z * 1048576;
#pragma unroll
    for (int mf = 0; mf < 4; ++mf)
#pragma unroll
        for (int nf = 0; nf < 4; ++nf)
#pragma unroll
            for (int e = 0; e < 4; ++e) {
                int o = o0 + wm * 64 + mf * 16 + g * 4 + e;
                int s = s0 + wn * 64 + nf * 16 + lr;
                qb[(long)o * 4096 + s] = __float2bfloat16(acc[mf][nf][e]);
            }
}

// ---------------------------------------------------------------------------
// K+V projection, fused transpose-convert of fmaps, double-buffered.
// grid (32 s-tiles, 64 bn), block 256.
// ---------------------------------------------------------------------------
__global__ __launch_bounds__(256) void kvproj(
    const float* __restrict__ fm,  // [64][256][4096]
    const bf16* __restrict__ Wk,   // [4][64][256]
    const bf16* __restrict__ Wv,   // [4][64][256]
    bf16* __restrict__ kb,         // [64][64][4096]
    bf16* __restrict__ vT)         // [64][4096][64]
{
    __shared__ bf16 sF[2][128 * 72];
    __shared__ bf16 sK[2][64 * 64];
    __shared__ bf16 sV[2][64 * 64];
    const int t = threadIdx.x;
    const int lane = t & 63, wid = t >> 6;
    const int g = lane >> 4, lr = lane & 15;
    const int s0 = blockIdx.x * 128;
    const int bn = blockIdx.y, n = bn & 3;
    const float* fb = fm + (long)bn * 1048576;
    const bf16* WkN = Wk + (long)n * 16384;
    const bf16* WvN = Wv + (long)n * 16384;

    f32x4 acc1[4][2];
    f32x4 acc2[2][4];
#pragma unroll
    for (int i = 0; i < 4; ++i)
#pragma unroll
        for (int j = 0; j < 2; ++j) {
            acc1[i][j] = (f32x4){0.f, 0.f, 0.f, 0.f};
            acc2[j][i] = (f32x4){0.f, 0.f, 0.f, 0.f};
        }

    const int p  = t & 31;
    const int sl = t >> 5;

    // prologue: stage c0=0 into buf 0
    {
#pragma unroll
        for (int i = 0; i < 2; ++i) {
            int lin = i * 256 + t, r = lin >> 3, ch = lin & 7;
            int off = r * 256 + ((ch ^ (r & 7)) << 3);
            gl_lds16(WkN + off, &sK[0][lin * 8]);
            gl_lds16(WvN + off, &sV[0][lin * 8]);
        }
        float4 ra[4], rb[4];
#pragma unroll
        for (int j = 0; j < 4; ++j) {
            const float* src = fb + (long)(2 * p) * 4096 + s0 + (j * 8 + sl) * 4;
            ra[j] = *(const float4*)src;
            rb[j] = *(const float4*)(src + 4096);
        }
#pragma unroll
        for (int j = 0; j < 4; ++j) {
            char* base = (char*)&sF[0][0] + p * 4 + ((j * 8 + sl) * 4) * 144;
            *(u32*)(base +   0) = pk2(ra[j].x, rb[j].x);
            *(u32*)(base + 144) = pk2(ra[j].y, rb[j].y);
            *(u32*)(base + 288) = pk2(ra[j].z, rb[j].z);
            *(u32*)(base + 432) = pk2(ra[j].w, rb[j].w);
        }
        __syncthreads();
    }

    int cur = 0;
    for (int it = 0; it < 4; ++it) {
        const int c0n = (it + 1) * 64;
        float4 ra[4], rb[4];
        if (it < 3) {
#pragma unroll
            for (int i = 0; i < 2; ++i) {
                int lin = i * 256 + t, r = lin >> 3, ch = lin & 7;
                int off = r * 256 + c0n + ((ch ^ (r & 7)) << 3);
                gl_lds16(WkN + off, &sK[cur ^ 1][lin * 8]);
                gl_lds16(WvN + off, &sV[cur ^ 1][lin * 8]);
            }
#pragma unroll
            for (int j = 0; j < 4; ++j) {
                const float* src = fb + (long)(c0n + 2 * p) * 4096 + s0 + (j * 8 + sl) * 4;
                ra[j] = *(const float4*)src;
                rb[j] = *(const float4*)(src + 4096);
            }
        }
        const char* fbase = (const char*)&sF[cur][0];
        const char* kbase = (const char*)&sK[cur][0];
        const char* vbase = (const char*)&sV[cur][0];
#pragma unroll
        for (int kk = 0; kk < 2; ++kk) {
            bf16x8 ak[4], ff[2], bv[4];
#pragma unroll
            for (int mf = 0; mf < 4; ++mf) {
                int r = mf * 16 + lr;
                ak[mf] = *(const bf16x8*)(kbase + r * 128 + (((kk * 4 + g) ^ (r & 7)) << 4));
            }
#pragma unroll
            for (int i = 0; i < 2; ++i) {
                int s = wid * 32 + i * 16 + lr;
                ff[i] = *(const bf16x8*)(fbase + s * 144 + (kk * 4 + g) * 16);
            }
#pragma unroll
            for (int nf = 0; nf < 4; ++nf) {
                int r = nf * 16 + lr;
                bv[nf] = *(const bf16x8*)(vbase + r * 128 + (((kk * 4 + g) ^ (r & 7)) << 4));
            }
#pragma unroll
            for (int mf = 0; mf < 4; ++mf)
#pragma unroll
                for (int i = 0; i < 2; ++i)
                    acc1[mf][i] = __builtin_amdgcn_mfma_f32_16x16x32_bf16(
                        ak[mf], ff[i], acc1[mf][i], 0, 0, 0);
#pragma unroll
            for (int i = 0; i < 2; ++i)
#pragma unroll
                for (int nf = 0; nf < 4; ++nf)
                    acc2[i][nf] = __builtin_amdgcn_mfma_f32_16x16x32_bf16(
                        ff[i], bv[nf], acc2[i][nf], 0, 0, 0);
        }
        if (it < 3) {
#pragma unroll
            for (int j = 0; j < 4; ++j) {
                char* base = (char*)&sF[cur ^ 1][0] + p * 4 + ((j * 8 + sl) * 4) * 144;
                *(u32*)(base +   0) = pk2(ra[j].x, rb[j].x);
                *(u32*)(base + 144) = pk2(ra[j].y, rb[j].y);
                *(u32*)(base + 288) = pk2(ra[j].z, rb[j].z);
                *(u32*)(base + 432) = pk2(ra[j].w, rb[j].w);
            }
            __syncthreads();
            cur ^= 1;
        }
    }

    bf16* kbb = kb + (long)bn * 262144;
#pragma unroll
    for (int mf = 0; mf < 4; ++mf)
#pragma unroll
        for (int i = 0; i < 2; ++i)
#pragma unroll
            for (int e = 0; e < 4; ++e) {
                int dd = mf * 16 + g * 4 + e;
                int s  = s0 + wid * 32 + i * 16 + lr;
                kbb[(long)dd * 4096 + s] = __float2bfloat16(acc1[mf][i][e]);
            }
    bf16* vtb = vT + (long)bn * 262144;
#pragma unroll
    for (int i = 0; i < 2; ++i)
#pragma unroll
        for (int nf = 0; nf < 4; ++nf)
#pragma unroll
            for (int e = 0; e < 4; ++e) {
                int s = s0 + wid * 32 + i * 16 + g * 4 + e;
                int ec = nf * 16 + lr;
                vtb[(long)s * 64 + ec] = __float2bfloat16(acc2[i][nf][e]);
            }
}

// ---------------------------------------------------------------------------
// QK^T partial + fused row sum-of-squares, 8 chunks, double-buffered.
// part[(bn*8+ch)][dd][e]; sumk_c/sumq_c[ch][bn*64+row] (no atomics).
// grid (8, 64), block 256 (4 waves 2x2, wave 32x32).
// ---------------------------------------------------------------------------
__global__ __launch_bounds__(256) void qk_sum(
    const bf16* __restrict__ kb,   // [64][64][4096]
    const bf16* __restrict__ qch,  // viewed as [64][64][4096]
    float* __restrict__ part,      // [64][8][64][64]
    float* __restrict__ sumq, float* __restrict__ sumk)  // [8][4096]
{
    __shared__ bf16 sA[2][64 * 64];
    __shared__ bf16 sB[2][64 * 64];
    const int t = threadIdx.x;
    const int lane = t & 63, wid = t >> 6;
    const int wm = wid >> 1, wn = wid & 1;
    const int g = lane >> 4, lr = lane & 15;
    const int ch_ = blockIdx.x;    // s-chunk 0..7 (512 s each)
    const int bn = blockIdx.y;
    const bf16* kbase = kb + (long)bn * 262144;
    const bf16* qbase = qch + (long)bn * 262144;

    const int srow = t >> 1;
    const int shalf = t & 1;

    f32x4 acc[2][2];
#pragma unroll
    for (int i = 0; i < 2; ++i)
#pragma unroll
        for (int j = 0; j < 2; ++j) acc[i][j] = (f32x4){0.f, 0.f, 0.f, 0.f};
    float ss = 0.f;

    // prologue: stage it=0
    {
        int k0 = ch_ * 512;
#pragma unroll
        for (int i = 0; i < 2; ++i) {
            int lin = i * 256 + t, r = lin >> 3, c = lin & 7;
            gl_lds16(kbase + (long)r * 4096 + k0 + ((c ^ (r & 7)) << 3), &sA[0][lin * 8]);
            gl_lds16(qbase + (long)r * 4096 + k0 + ((c ^ (r & 7)) << 3), &sB[0][lin * 8]);
        }
        __syncthreads();
    }

    int cur = 0;
    for (int it = 0; it < 8; ++it) {
        if (it < 7) {
            int k0 = ch_ * 512 + (it + 1) * 64;
#pragma unroll
            for (int i = 0; i < 2; ++i) {
                int lin = i * 256 + t, r = lin >> 3, c = lin & 7;
                gl_lds16(kbase + (long)r * 4096 + k0 + ((c ^ (r & 7)) << 3), &sA[cur ^ 1][lin * 8]);
                gl_lds16(qbase + (long)r * 4096 + k0 + ((c ^ (r & 7)) << 3), &sB[cur ^ 1][lin * 8]);
            }
        }
        const char* abase = (const char*)&sA[cur][0];
        const char* bbase = (const char*)&sB[cur][0];
#pragma unroll
        for (int kk = 0; kk < 2; ++kk) {
            bf16x8 af[2], bf[2];
#pragma unroll
            for (int mf = 0; mf < 2; ++mf) {
                int r = wm * 32 + mf * 16 + lr;
                af[mf] = *(const bf16x8*)(abase + r * 128 + (((kk * 4 + g) ^ (r & 7)) << 4));
            }
#pragma unroll
            for (int nf = 0; nf < 2; ++nf) {
                int r = wn * 32 + nf * 16 + lr;
                bf[nf] = *(const bf16x8*)(bbase + r * 128 + (((kk * 4 + g) ^ (r & 7)) << 4));
            }
#pragma unroll
            for (int mf = 0; mf < 2; ++mf)
#pragma unroll
                for (int nf = 0; nf < 2; ++nf)
                    acc[mf][nf] = __builtin_amdgcn_mfma_f32_16x16x32_bf16(
                        af[mf], bf[nf], acc[mf][nf], 0, 0, 0);
        }
        // fused sumsq on current buffer
        {
            const char* base = (srow < 64) ? abase + srow * 128
                                           : bbase + (srow - 64) * 128;
            int r7 = srow & 7;
#pragma unroll
            for (int j = 0; j < 4; ++j) {
                bf16x8 v = *(const bf16x8*)(base + (((shalf * 4 + j) ^ r7) << 4));
#pragma unroll
                for (int e = 0; e < 8; ++e) {
                    float f = b2f((u16)v[e]);
                    ss += f * f;
                }
            }
        }
        __syncthreads();
        cur ^= 1;
    }

    ss += __shfl_xor(ss, 1);
    if (shalf == 0) {
        if (srow < 64) sumk[ch_ * 4096 + bn * 64 + srow] = ss;
        else           sumq[ch_ * 4096 + bn * 64 + srow - 64] = ss;
    }
    float* pp = part + ((long)bn * 8 + ch_) * 4096;
#pragma unroll
    for (int mf = 0; mf < 2; ++mf)
#pragma unroll
        for (int nf = 0; nf < 2; ++nf)
#pragma unroll
            for (int e = 0; e < 4; ++e) {
                int m = wm * 32 + mf * 16 + g * 4 + e;
                int nn = wn * 32 + nf * 16 + lr;
                pp[m * 64 + nn] = acc[mf][nf][e];
            }
}

// ---------------------------------------------------------------------------
// finalize: sum 8 partials, rsqrt norms, scale, softmax -> bf16
// ---------------------------------------------------------------------------
__global__ __launch_bounds__(256) void attn_finalize_kernel(
    const float* __restrict__ part,  // [64][8][64][64]
    const float* __restrict__ sumq, const float* __restrict__ sumk, // [8][4096]
    const float* __restrict__ rescale,
    bf16* __restrict__ attn_out)
{
    const int bn = blockIdx.x;
    const int n = bn & 3;
    const int t = threadIdx.x;
    const float rs = rescale[n];

    __shared__ float att[64][65];
    __shared__ float rmax[64], rsum[64];
    __shared__ float iq[64], ik[64];

    if (t < 64) {
        float s = 0.f;
#pragma unroll
        for (int c = 0; c < 8; ++c) s += sumk[c * 4096 + bn * 64 + t];
        ik[t] = 1.f / fmaxf(sqrtf(s), 1e-12f);
    } else if (t < 128) {
        float s = 0.f;
#pragma unroll
        for (int c = 0; c < 8; ++c) s += sumq[c * 4096 + bn * 64 + t - 64];
        iq[t - 64] = 1.f / fmaxf(sqrtf(s), 1e-12f);
    }
    __syncthreads();

    const float* pb = part + (size_t)bn * 8 * 4096;
#pragma unroll
    for (int p = 0; p < 16; ++p) {
        int lin = p * 256 + t;
        int dd = lin >> 6, e = lin & 63;
        float v = 0.f;
#pragma unroll
        for (int c = 0; c < 8; ++c) v += pb[c * 4096 + lin];
        v *= ik[dd] * iq[e] * rs;
        att[dd][e] = v;
    }
    __syncthreads();
    if (t < 64) {
        float m = -1e30f;
        for (int e = 0; e < 64; ++e) m = fmaxf(m, att[t][e]);
        float sm = 0.f;
        for (int e = 0; e < 64; ++e) sm += expf(att[t][e] - m);
        rmax[t] = m;
        rsum[t] = 1.0f / sm;
    }
    __syncthreads();
    bf16* ob = attn_out + (size_t)bn * 4096;
#pragma unroll
    for (int p = 0; p < 16; ++p) {
        int lin = p * 256 + t;
        int dd = lin >> 6, e = lin & 63;
        ob[lin] = __float2bfloat16(expf(att[dd][e] - rmax[dd]) * rsum[dd]);
    }
}

// ---------------------------------------------------------------------------
// Fused PV + FFN, prefetched: 2 barriers per head.
// grid (32 s-tiles, 16 b), block 256.
// ---------------------------------------------------------------------------
__global__ __launch_bounds__(256) void pvffn(
    const bf16* __restrict__ vT,    // [64][4096][64]
    const bf16* __restrict__ attnb, // [64][64][64]
    const bf16* __restrict__ qch,   // [16][256][4096]
    const bf16* __restrict__ Wf,    // [256][256]
    const float* __restrict__ bffn, // [256]
    float* __restrict__ out)        // [16][256][4096]
{
    __shared__ bf16 bufA[2][12288]; // per buf: [0:8192) vT tile, [8192:12288) attn
    __shared__ bf16 Zs[128 * 64];   // XOR-swizzled
    const int t = threadIdx.x;
    const int lane = t & 63, wid = t >> 6;
    const int g = lane >> 4, lr = lane & 15;
    const int s0 = blockIdx.x * 128;
    const int b = blockIdx.y;

    f32x4 accF[4][8];
#pragma unroll
    for (int i = 0; i < 4; ++i)
#pragma unroll
        for (int j = 0; j < 8; ++j) accF[i][j] = (f32x4){0.f, 0.f, 0.f, 0.f};

    // prologue: stage head 0
    {
        const int bn = b * 4;
#pragma unroll
        for (int i = 0; i < 4; ++i) {
            int lin = i * 256 + t, r = lin >> 3, c = lin & 7;
            gl_lds16(vT + (long)bn * 262144 + (long)(s0 + r) * 64 + ((c ^ (r & 7)) << 3),
                     &bufA[0][lin * 8]);
        }
#pragma unroll
        for (int i = 0; i < 2; ++i) {
            int lin = i * 256 + t, r = lin >> 3, c = lin & 7;
            gl_lds16(attnb + (long)bn * 4096 + r * 64 + ((c ^ (r & 7)) << 3),
                     &bufA[0][8192 + lin * 8]);
        }
        __syncthreads();
    }

    for (int n = 0; n < 4; ++n) {
        const int bn = b * 4 + n;
        const int cur = n & 1;
        // prefetch next head's vT + attn
        if (n < 3) {
            const int bnn = bn + 1;
#pragma unroll
            for (int i = 0; i < 4; ++i) {
                int lin = i * 256 + t, r = lin >> 3, c = lin & 7;
                gl_lds16(vT + (long)bnn * 262144 + (long)(s0 + r) * 64 + ((c ^ (r & 7)) << 3),
                         &bufA[cur ^ 1][lin * 8]);
            }
#pragma unroll
            for (int i = 0; i < 2; ++i) {
                int lin = i * 256 + t, r = lin >> 3, c = lin & 7;
                gl_lds16(attnb + (long)bnn * 4096 + r * 64 + ((c ^ (r & 7)) << 3),
                         &bufA[cur ^ 1][8192 + lin * 8]);
            }
        }
        // Wf fragments for this head straight from global (L2-resident)
        bf16x8 wf[2][4];
#pragma unroll
        for (int kk = 0; kk < 2; ++kk)
#pragma unroll
            for (int mf = 0; mf < 4; ++mf)
                wf[kk][mf] = *(const bf16x8*)(
                    Wf + (long)(wid * 64 + mf * 16 + lr) * 256 + n * 64 + (kk * 4 + g) * 8);

        // PV: wave wid owns s-rows wid*32..+31
        const char* vb = (const char*)&bufA[cur][0];
        const char* ab = vb + 16384;
        f32x4 accP[2][4];
#pragma unroll
        for (int i = 0; i < 2; ++i)
#pragma unroll
            for (int j = 0; j < 4; ++j) accP[i][j] = (f32x4){0.f, 0.f, 0.f, 0.f};
#pragma unroll
        for (int kk = 0; kk < 2; ++kk) {
            bf16x8 av[2], at[4];
#pragma unroll
            for (int mf = 0; mf < 2; ++mf) {
                int r = wid * 32 + mf * 16 + lr;
                av[mf] = *(const bf16x8*)(vb + r * 128 + (((kk * 4 + g) ^ (r & 7)) << 4));
            }
#pragma unroll
            for (int nf = 0; nf < 4; ++nf) {
                int r = nf * 16 + lr;
                at[nf] = *(const bf16x8*)(ab + r * 128 + (((kk * 4 + g) ^ (r & 7)) << 4));
            }
#pragma unroll
            for (int mf = 0; mf < 2; ++mf)
#pragma unroll
                for (int nf = 0; nf < 4; ++nf)
                    accP[mf][nf] = __builtin_amdgcn_mfma_f32_16x16x32_bf16(
                        av[mf], at[nf], accP[mf][nf], 0, 0, 0);
        }
        // write Z slice (+ q residual) into swizzled Zs
#pragma unroll
        for (int mf = 0; mf < 2; ++mf)
#pragma unroll
            for (int nf = 0; nf < 4; ++nf) {
                int slb = wid * 32 + mf * 16 + g * 4;
                int il = nf * 16 + lr;
                ushort4 qv = *(const ushort4*)(qch + ((long)b * 256 + n * 64 + il) * 4096 + s0 + slb);
                u16 qa[4] = {qv.x, qv.y, qv.z, qv.w};
#pragma unroll
                for (int e = 0; e < 4; ++e) {
                    int sl = slb + e;
                    float v = accP[mf][nf][e] + b2f(qa[e]);
                    bf16 hv = __float2bfloat16(v);
                    int byte = sl * 128 + ((((il >> 3) ^ (sl & 7))) << 4) + (il & 7) * 2;
                    *(u16*)((char*)Zs + byte) = *(u16*)&hv;
                }
            }
        __syncthreads();   // B1: Zs visible; prefetch drained
        // FFN partial: wave wid owns c-rows wid*64..+63
#pragma unroll
        for (int kk = 0; kk < 2; ++kk) {
            bf16x8 bz[8];
#pragma unroll
            for (int nf = 0; nf < 8; ++nf) {
                int sl = nf * 16 + lr;
                bz[nf] = *(const bf16x8*)((const char*)Zs + sl * 128 + (((kk * 4 + g) ^ (sl & 7)) << 4));
            }
#pragma unroll
            for (int mf = 0; mf < 4; ++mf)
#pragma unroll
                for (int nf = 0; nf < 8; ++nf)
                    accF[mf][nf] = __builtin_amdgcn_mfma_f32_16x16x32_bf16(
                        wf[kk][mf], bz[nf], accF[mf][nf], 0, 0, 0);
        }
        __syncthreads();   // B2: FFN reads done before next head's Zs writes
    }

    float* ob = out + (long)b * 1048576;
    const bf16* qb = qch + (long)b * 1048576;
#pragma unroll
    for (int mf = 0; mf < 4; ++mf)
#pragma unroll
        for (int e = 0; e < 4; ++e) {
            int c = wid * 64 + mf * 16 + g * 4 + e;
            float bv = bffn[c];
#pragma unroll
            for (int nf = 0; nf < 8; ++nf) {
                int s = s0 + nf * 16 + lr;
                long idx = (long)c * 4096 + s;
                ob[idx] = accF[mf][nf][e] + bv + b2f(*(const u16*)(qb + idx));
            }
        }
}

// ---------------------------------------------------------------------------
__global__ __launch_bounds__(256) void wconv(
    const float* __restrict__ a, const float* __restrict__ b,
    const float* __restrict__ c, const float* __restrict__ d,
    bf16* __restrict__ o)
{
    int i = blockIdx.x * 256 + threadIdx.x;
    int which = i >> 16, off = i & 65535;
    const float* s = (which == 0) ? a : (which == 1) ? b : (which == 2) ? c : d;
    o[i] = __float2bfloat16(s[off]);
}

// ---------------------------------------------------------------------------
extern "C" void kernel_launch(void* const* d_in, const int* in_sizes, int n_in,
                              void* d_out, int out_size, void* d_ws, size_t ws_size,
                              hipStream_t stream) {
    const float* x       = (const float*)d_in[0];
    const float* fmaps   = (const float*)d_in[1];
    const float* Wq      = (const float*)d_in[2];
    const float* Wk      = (const float*)d_in[3];
    const float* Wv      = (const float*)d_in[4];
    const float* rescale = (const float*)d_in[5];
    const float* Wffn    = (const float*)d_in[6];
    const float* bffn    = (const float*)d_in[7];
    float* out = (float*)d_out;

    char* w = (char*)d_ws;
    bf16* kbuf  = (bf16*)(w + 0);             // 33.55 MB
    bf16* vT    = (bf16*)(w + 33554432L);     // 33.55 MB
    bf16* qch   = (bf16*)(w + 67108864L);     // 33.55 MB
    float* part = (float*)(w + 100663296L);   // 64*8*4096*4 = 8.39 MB
    bf16* attnb = (bf16*)(w + 109051904L);    // 512 KB
    float* sumq = (float*)(w + 109576192L);   // 8*4096*4 = 128 KB
    float* sumk = (float*)(w + 109707264L);   // 128 KB
    bf16* Wq_b  = (bf16*)(w + 109838336L);
    bf16* Wk_b  = Wq_b + 65536;
    bf16* Wv_b  = Wq_b + 131072;
    bf16* Wf_b  = Wq_b + 196608;

    dim3 blk(256);

    // 1. weights -> bf16
    wconv<<<dim3(1024), blk, 0, stream>>>(Wq, Wk, Wv, Wffn, Wq_b);
    // 2. K/V projections, fmaps read once
    kvproj<<<dim3(32, 64), blk, 0, stream>>>(fmaps, Wk_b, Wv_b, kbuf, vT);
    // 3. Q projection
    qproj<<<dim3(32, 2, 16), blk, 0, stream>>>(x, Wq_b, qch);
    // 4. QK^T partials + fused row sumsq (8 chunks, no atomics)
    qk_sum<<<dim3(8, 64), blk, 0, stream>>>(kbuf, qch, part, sumq, sumk);
    // 5. finalize: rsqrt + scale + softmax -> attn bf16
    attn_finalize_kernel<<<dim3(64), blk, 0, stream>>>(part, sumq, sumk, rescale, attnb);
    // 6. fused PV + FFN -> out f32
    pvffn<<<dim3(32, 16), blk, 0, stream>>>(vT, attnb, qch, Wf_b, bffn, out);
}